// Round 10
// baseline (322.315 us; speedup 1.0000x reference)
//
#include <hip/hip_runtime.h>
#include <hip/hip_bf16.h>

#define BS   16
#define NA   8400
#define NMB  100
#define NC   80
#define TOPK 13
#define EPS  1e-9f
#define NBLK 512

typedef float f32x4 __attribute__((ext_vector_type(4)));

// output layout (floats): labels [BS,NA] | bboxes [BS,NA,4] | scores [BS,NA,NC] | fg [BS,NA]
#define OUT_LABELS 0
#define OUT_BBOX   (BS * NA)
#define OUT_SCORES (BS * NA * 5)
#define OUT_FG     (BS * NA * 5 + BS * NA * NC)

// ws (u32 units): cm[BS*NA] | posalign[1600] | posover[1600] | bar[4] | alignbuf | idxbuf
#define CM_OFF   0
#define PA_OFF   (BS * NA)
#define PO_OFF   (BS * NA + BS * NMB)
#define BAR_OFF  (BS * NA + 2 * BS * NMB)     // 137600
#define AB_OFF   (BAR_OFF + 4)
#define IDX_OFF  (AB_OFF + BS * NA)

#define INIT_U32 (BAR_OFF + 4)                // 137604, divisible by 4
#define INIT_VEC (INIT_U32 / 4)               // 34401

__device__ __forceinline__ float iou_xyxy(float4 g, float4 p) {
    float lx = fmaxf(g.x, p.x), ly = fmaxf(g.y, p.y);
    float rx = fminf(g.z, p.z), ry = fminf(g.w, p.w);
    float w = fmaxf(rx - lx, 0.f), h = fmaxf(ry - ly, 0.f);
    float inter = w * h;
    float ag = (g.z - g.x) * (g.w - g.y);
    float ap = (p.z - p.x) * (p.w - p.y);
    return inter / (ag + ap - inter + EPS);
}

// fast unsigned divide for small c (<4096), w (<128): rcp + correction
__device__ __forceinline__ void fdivmod(int c, int w, float rw, int& q, int& r) {
    q = (int)((float)c * rw);
    r = c - q * w;
    if (r < 0) { q--; r += w; }
    else if (r >= w) { q++; r -= w; }
}

// Monotonic-counter grid barrier. Safe: all NBLK blocks are co-resident
// (launch_bounds(256,2) -> 2 blocks/CU -> 512 blocks on 256 CUs), counters
// zeroed by k_init each call. Device-scope atomics + threadfence handle
// cross-XCD visibility.
__device__ __forceinline__ void grid_barrier(unsigned* bar, unsigned target) {
    __syncthreads();
    if (threadIdx.x == 0) {
        __threadfence();                       // release this block's writes
        atomicAdd(bar, 1u);
        while (__hip_atomic_load(bar, __ATOMIC_ACQUIRE,
                                 __HIP_MEMORY_SCOPE_AGENT) < target)
            __builtin_amdgcn_s_sleep(4);
        __threadfence();
    }
    __syncthreads();
}

// Zero cm + posalign + posover + barrier counters (550 KB).
__global__ __launch_bounds__(256) void k_init(uint4* __restrict__ ws) {
    int t = blockIdx.x * 256 + threadIdx.x;
    if (t < INIT_VEC) ws[t] = make_uint4(0u, 0u, 0u, 0u);
}

// Persistent fused kernel: phase1 topk | barrier | phase2 resolve | barrier |
// phase3 score. 512 blocks x 256 threads, all co-resident.
__global__ __launch_bounds__(256, 2) void k_fused(
        const float* __restrict__ scores, const float* __restrict__ pboxes,
        const float* __restrict__ gboxes, const float* __restrict__ maskgt,
        const int* __restrict__ glabels,
        unsigned int* __restrict__ ws, float* __restrict__ out) {
    unsigned int* cm       = ws + CM_OFF;
    unsigned int* posalign = ws + PA_OFF;
    unsigned int* posover  = ws + PO_OFF;
    unsigned int* bar      = ws + BAR_OFF;
    float*        alignbuf = (float*)(ws + AB_OFF);
    int*          idxbuf   = (int*)(ws + IDX_OFF);
    const float4* gb4 = (const float4*)gboxes;

    // ---------------- phase 1: top-k per GT (one wave per GT) ----------------
    {
        int w = blockIdx.x * 4 + (threadIdx.x >> 6);
        if (w < BS * NMB) {
            int bm = (w & 7) * 200 + (w >> 3);     // XCD spread
            float mg = maskgt[bm];
            float4 g = gb4[bm];
            int lbl = glabels[bm];
            if (mg > 0.f) {
                int b = bm / NMB, mm = bm - b * NMB;
                int lane = threadIdx.x & 63;
                const float* srow = scores + (size_t)b * NA * NC + lbl;
                const float4* pb = (const float4*)pboxes + (size_t)b * NA;

                // padded per-level index ranges; ins test is the exact filter
                int x0, y0, w0, h0, x1r, y1r, w1, h1, x2r, y2r, w2, h2;
                {
                    float s = 8.f; int n = 80;
                    x0 = (int)floorf((g.x + EPS) / s - 0.5f); if (x0 < 0) x0 = 0;
                    int xh = (int)ceilf((g.z - EPS) / s - 0.5f); if (xh > n - 1) xh = n - 1;
                    y0 = (int)floorf((g.y + EPS) / s - 0.5f); if (y0 < 0) y0 = 0;
                    int yh = (int)ceilf((g.w - EPS) / s - 0.5f); if (yh > n - 1) yh = n - 1;
                    w0 = xh - x0 + 1; if (w0 < 0) w0 = 0;
                    h0 = yh - y0 + 1; if (h0 < 0) h0 = 0;
                }
                {
                    float s = 16.f; int n = 40;
                    x1r = (int)floorf((g.x + EPS) / s - 0.5f); if (x1r < 0) x1r = 0;
                    int xh = (int)ceilf((g.z - EPS) / s - 0.5f); if (xh > n - 1) xh = n - 1;
                    y1r = (int)floorf((g.y + EPS) / s - 0.5f); if (y1r < 0) y1r = 0;
                    int yh = (int)ceilf((g.w - EPS) / s - 0.5f); if (yh > n - 1) yh = n - 1;
                    w1 = xh - x1r + 1; if (w1 < 0) w1 = 0;
                    h1 = yh - y1r + 1; if (h1 < 0) h1 = 0;
                }
                {
                    float s = 32.f; int n = 20;
                    x2r = (int)floorf((g.x + EPS) / s - 0.5f); if (x2r < 0) x2r = 0;
                    int xh = (int)ceilf((g.z - EPS) / s - 0.5f); if (xh > n - 1) xh = n - 1;
                    y2r = (int)floorf((g.y + EPS) / s - 0.5f); if (y2r < 0) y2r = 0;
                    int yh = (int)ceilf((g.w - EPS) / s - 0.5f); if (yh > n - 1) yh = n - 1;
                    w2 = xh - x2r + 1; if (w2 < 0) w2 = 0;
                    h2 = yh - y2r + 1; if (h2 < 0) h2 = 0;
                }
                int n0 = w0 * h0, n01 = n0 + w1 * h1, n012 = n01 + w2 * h2;
                int N = n012 + TOPK;               // <= ~583 + 13 <= 640
                float rw0 = __builtin_amdgcn_rcpf((float)w0);
                float rw1 = __builtin_amdgcn_rcpf((float)w1);
                float rw2 = __builtin_amdgcn_rcpf((float)w2);

                // pass A: addresses only (branchy, no loads)
                int aarr[10]; float axv[10], ayv[10];
                unsigned validm = 0;
                #pragma unroll
                for (int j = 0; j < 10; ++j) {
                    aarr[j] = 0; axv[j] = 0.f; ayv[j] = 0.f;
                    int c = lane + j * 64;
                    if (c < N) {
                        int a; float ax, ay; bool dup = false;
                        if (c < n0) {
                            int iy, ix; fdivmod(c, w0, rw0, iy, ix);
                            iy += y0; ix += x0;
                            a = iy * 80 + ix; ax = (ix + 0.5f) * 8.f; ay = (iy + 0.5f) * 8.f;
                        } else if (c < n01) {
                            int iy, ix; fdivmod(c - n0, w1, rw1, iy, ix);
                            iy += y1r; ix += x1r;
                            a = 6400 + iy * 40 + ix; ax = (ix + 0.5f) * 16.f; ay = (iy + 0.5f) * 16.f;
                        } else if (c < n012) {
                            int iy, ix; fdivmod(c - n01, w2, rw2, iy, ix);
                            iy += y2r; ix += x2r;
                            a = 8000 + iy * 20 + ix; ax = (ix + 0.5f) * 32.f; ay = (iy + 0.5f) * 32.f;
                        } else {
                            a = c - n012;          // supplement: L0 row 0, ix=a
                            ax = (a + 0.5f) * 8.f; ay = 4.0f;
                            dup = (h0 > 0) && (y0 == 0) && (w0 > 0) &&
                                  (x0 <= a) && (a <= x0 + w0 - 1);
                        }
                        if (!dup) { aarr[j] = a; axv[j] = ax; ayv[j] = ay; validm |= 1u << j; }
                    }
                }
                // pass B: all 20 gathers issued back-to-back (a=0 for invalid)
                float4 pv[10]; float sv[10];
                #pragma unroll
                for (int j = 0; j < 10; ++j) {
                    pv[j] = pb[aarr[j]];
                    sv[j] = srow[(size_t)aarr[j] * NC];
                }
                // pass C: values + packed keys
                unsigned long long key[10];
                unsigned insmask = 0;
                #pragma unroll
                for (int j = 0; j < 10; ++j) {
                    key[j] = 0ull;
                    if (validm & (1u << j)) {
                        float ov = iou_xyxy(g, pv[j]);
                        bool ins = fminf(fminf(axv[j] - g.x, ayv[j] - g.y),
                                         fminf(g.z - axv[j], g.w - ayv[j])) > EPS;
                        float o2 = ov * ov;
                        float val = ins ? sv[j] * o2 * o2 * o2 : 0.f;
                        key[j] = ((unsigned long long)__float_as_uint(val) << 32)
                               | (unsigned)(0xFFFFFFFFu - (unsigned)aarr[j]);
                        if (ins) insmask |= (1u << j);
                    }
                }
                // 13 rounds of wave argmax (exact top_k order: value desc, idx asc)
                for (int r = 0; r < TOPK; ++r) {
                    unsigned long long best = 0ull;
                    #pragma unroll
                    for (int j = 0; j < 10; ++j) if (key[j] > best) best = key[j];
                    #pragma unroll
                    for (int off = 32; off >= 1; off >>= 1) {
                        unsigned long long o = __shfl_xor(best, off, 64);
                        if (o > best) best = o;
                    }
                    #pragma unroll
                    for (int j = 0; j < 10; ++j) {
                        if (key[j] == best) {      // unique owner
                            key[j] = 0ull;
                            if ((insmask >> j) & 1u) {
                                int a = (int)(0xFFFFFFFFu - (unsigned)best);
                                atomicAdd(&cm[b * NA + a], (1u << 20) | (unsigned)mm);
                            }
                        }
                    }
                }
            }
        }
    }
    grid_barrier(bar + 0, NBLK);

    // ---------------- phase 2: collision resolution + gathers ----------------
    for (int t = blockIdx.x * 256 + threadIdx.x; t < BS * NA; t += NBLK * 256) {
        int b = t / NA;
        unsigned c = cm[t];
        int cnt = (int)(c >> 20);
        float4 p = ((const float4*)pboxes)[t];
        int idx = 0, fg = 0;
        if (cnt == 1) { idx = (int)(c & 0xFFFFFu); fg = 1; }
        else if (cnt > 1) {
            float best = -1.f; int bmx = 0;
            for (int m = 0; m < NMB; ++m) {
                float ov = iou_xyxy(gb4[b * NMB + m], p);   // L2-resident
                if (ov > best) { best = ov; bmx = m; }
            }
            idx = bmx; fg = 1;
        }
        int lbl = glabels[b * NMB + idx];
        if (lbl < 0) lbl = 0;
        float4 gbx = gb4[b * NMB + idx];
        float al = 0.f;
        if (fg) {
            float ov = iou_xyxy(gbx, p);
            float sc = scores[(size_t)t * NC + lbl];
            float o2 = ov * ov;
            al = sc * o2 * o2 * o2;            // UNMASKED align (matches ref)
            atomicMax(&posalign[b * NMB + idx], __float_as_uint(al));
            atomicMax(&posover[b * NMB + idx], __float_as_uint(ov));
        }
        alignbuf[t] = al;
        idxbuf[t] = fg ? idx : -1;
        out[OUT_LABELS + t] = (float)lbl;      // gather NOT masked by fg (ref)
        ((float4*)(out + OUT_BBOX))[t] = gbx;
        out[OUT_FG + t] = fg ? 1.f : 0.f;
    }
    grid_barrier(bar + 1, NBLK);

    // ---------------- phase 3: normalized one-hot score write ----------------
    for (int i = blockIdx.x * 256 + threadIdx.x; i < BS * NA * (NC / 4);
         i += NBLK * 256) {
        int t = i / (NC / 4), q = i - t * (NC / 4);
        int b = t / NA;
        int idx = idxbuf[t];
        float norm = 0.f; int lbl = -1;
        if (idx >= 0) {
            float pa = __uint_as_float(posalign[b * NMB + idx]);
            float po = __uint_as_float(posover[b * NMB + idx]);
            norm = alignbuf[t] * po / (pa + EPS);
            lbl = glabels[b * NMB + idx];
            if (lbl < 0) lbl = 0;
        }
        int c0 = q * 4;
        f32x4 w;
        w.x = (c0     == lbl) ? norm : 0.f;
        w.y = (c0 + 1 == lbl) ? norm : 0.f;
        w.z = (c0 + 2 == lbl) ? norm : 0.f;
        w.w = (c0 + 3 == lbl) ? norm : 0.f;
        ((f32x4*)(out + OUT_SCORES))[i] = w;
    }
}

extern "C" void kernel_launch(void* const* d_in, const int* in_sizes, int n_in,
                              void* d_out, int out_size, void* d_ws, size_t ws_size,
                              hipStream_t stream) {
    const float* scores  = (const float*)d_in[0];   // [BS,NA,NC]
    const float* pboxes  = (const float*)d_in[1];   // [BS,NA,4]
    const float* gboxes  = (const float*)d_in[3];   // [BS,NMB,4]
    const float* maskgt  = (const float*)d_in[4];   // [BS,NMB,1]
    const int*   glabels = (const int*)d_in[5];     // [BS,NMB,1]
    float* out = (float*)d_out;

    k_init<<<(INIT_VEC + 255) / 256, 256, 0, stream>>>((uint4*)d_ws);
    k_fused<<<NBLK, 256, 0, stream>>>(scores, pboxes, gboxes, maskgt, glabels,
                                      (unsigned int*)d_ws, out);
}

// Round 11
// 136.627 us; speedup vs baseline: 2.3591x; 2.3591x over previous
//
#include <hip/hip_runtime.h>
#include <hip/hip_bf16.h>

#define BS   16
#define NA   8400
#define NMB  100
#define NC   80
#define TOPK 13
#define EPS  1e-9f
#define NBLK 525                              // 525*256 == BS*NA exactly

typedef float f32x4 __attribute__((ext_vector_type(4)));

// output layout (floats): labels [BS,NA] | bboxes [BS,NA,4] | scores [BS,NA,NC] | fg [BS,NA]
#define OUT_LABELS 0
#define OUT_BBOX   (BS * NA)
#define OUT_SCORES (BS * NA * 5)
#define OUT_FG     (BS * NA * 5 + BS * NA * NC)

// ws (u32 units): cm[BS*NA] | posalign[1600] | posover[1600] | bar[8]
#define CM_OFF   0
#define PA_OFF   (BS * NA)                    // 134400
#define PO_OFF   (BS * NA + BS * NMB)         // 136000
#define BAR_OFF  (BS * NA + 2 * BS * NMB)     // 137600
#define INIT_U32 (BAR_OFF + 8)                // 137608, divisible by 8
#define INIT_VEC (INIT_U32 / 4)               // 34402

__device__ __forceinline__ float iou_xyxy(float4 g, float4 p) {
    float lx = fmaxf(g.x, p.x), ly = fmaxf(g.y, p.y);
    float rx = fminf(g.z, p.z), ry = fminf(g.w, p.w);
    float w = fmaxf(rx - lx, 0.f), h = fmaxf(ry - ly, 0.f);
    float inter = w * h;
    float ag = (g.z - g.x) * (g.w - g.y);
    float ap = (p.z - p.x) * (p.w - p.y);
    return inter / (ag + ap - inter + EPS);
}

// fast unsigned divide for small c (<4096), w (<128): rcp + correction
__device__ __forceinline__ void fdivmod(int c, int w, float rw, int& q, int& r) {
    q = (int)((float)c * rw);
    r = c - q * w;
    if (r < 0) { q--; r += w; }
    else if (r >= w) { q++; r -= w; }
}

// Fence-free grid barrier. Correctness: ALL cross-phase data flows through
// device-scope atomics (performed at the coherence point) or stays in the
// same thread's registers -- so no L2 writeback (__threadfence) is needed.
// s_waitcnt vmcnt(0) drains this wave's outstanding atomics before arrival.
// RELAXED add + RELAXED poll avoid the per-poll cache-invalidate that made
// the acquire/release version take ~140us per barrier.
__device__ __forceinline__ void gbar(unsigned* flag, unsigned target) {
    __syncthreads();
    if (threadIdx.x == 0) {
        asm volatile("s_waitcnt vmcnt(0)" ::: "memory");
        __hip_atomic_fetch_add(flag, 1u, __ATOMIC_RELAXED,
                               __HIP_MEMORY_SCOPE_AGENT);
        unsigned v;
        do {
            __builtin_amdgcn_s_sleep(16);      // ~1024 clk between polls
            v = __hip_atomic_load(flag, __ATOMIC_RELAXED,
                                  __HIP_MEMORY_SCOPE_AGENT);
        } while (v < target);
        asm volatile("" ::: "memory");         // compiler fence only
    }
    __syncthreads();
}

// Zero cm + posalign + posover + barrier flags (551 KB).
__global__ __launch_bounds__(256) void k_init(uint4* __restrict__ ws) {
    int t = blockIdx.x * 256 + threadIdx.x;
    if (t < INIT_VEC) ws[t] = make_uint4(0u, 0u, 0u, 0u);
}

// Persistent fused kernel: phase1 topk | bar | phase2 resolve | bar | phase3
// score. 525 blocks x 256 threads; launch_bounds(256,4) caps VGPR at 128 ->
// 4 blocks/CU -> all 525 co-resident (capacity 1024).
__global__ __launch_bounds__(256, 4) void k_fused(
        const float* __restrict__ scores, const float* __restrict__ pboxes,
        const float* __restrict__ gboxes, const float* __restrict__ maskgt,
        const int* __restrict__ glabels,
        unsigned int* __restrict__ ws, float* __restrict__ out) {
    unsigned int* cm       = ws + CM_OFF;
    unsigned int* posalign = ws + PA_OFF;
    unsigned int* posover  = ws + PO_OFF;
    unsigned int* bar      = ws + BAR_OFF;
    const float4* gb4 = (const float4*)gboxes;

    // ---------------- phase 1: top-k per GT (one wave per GT) ----------------
    {
        int w = blockIdx.x * 4 + (threadIdx.x >> 6);
        if (w < BS * NMB) {
            int bm = (w & 7) * 200 + (w >> 3);     // XCD spread
            float mg = maskgt[bm];
            float4 g = gb4[bm];
            int lbl = glabels[bm];
            if (mg > 0.f) {
                int b = bm / NMB, mm = bm - b * NMB;
                int lane = threadIdx.x & 63;
                const float* srow = scores + (size_t)b * NA * NC + lbl;
                const float4* pb = (const float4*)pboxes + (size_t)b * NA;

                // padded per-level index ranges; ins test is the exact filter
                int x0, y0, w0, h0, x1r, y1r, w1, h1, x2r, y2r, w2, h2;
                {
                    float s = 8.f; int n = 80;
                    x0 = (int)floorf((g.x + EPS) / s - 0.5f); if (x0 < 0) x0 = 0;
                    int xh = (int)ceilf((g.z - EPS) / s - 0.5f); if (xh > n - 1) xh = n - 1;
                    y0 = (int)floorf((g.y + EPS) / s - 0.5f); if (y0 < 0) y0 = 0;
                    int yh = (int)ceilf((g.w - EPS) / s - 0.5f); if (yh > n - 1) yh = n - 1;
                    w0 = xh - x0 + 1; if (w0 < 0) w0 = 0;
                    h0 = yh - y0 + 1; if (h0 < 0) h0 = 0;
                }
                {
                    float s = 16.f; int n = 40;
                    x1r = (int)floorf((g.x + EPS) / s - 0.5f); if (x1r < 0) x1r = 0;
                    int xh = (int)ceilf((g.z - EPS) / s - 0.5f); if (xh > n - 1) xh = n - 1;
                    y1r = (int)floorf((g.y + EPS) / s - 0.5f); if (y1r < 0) y1r = 0;
                    int yh = (int)ceilf((g.w - EPS) / s - 0.5f); if (yh > n - 1) yh = n - 1;
                    w1 = xh - x1r + 1; if (w1 < 0) w1 = 0;
                    h1 = yh - y1r + 1; if (h1 < 0) h1 = 0;
                }
                {
                    float s = 32.f; int n = 20;
                    x2r = (int)floorf((g.x + EPS) / s - 0.5f); if (x2r < 0) x2r = 0;
                    int xh = (int)ceilf((g.z - EPS) / s - 0.5f); if (xh > n - 1) xh = n - 1;
                    y2r = (int)floorf((g.y + EPS) / s - 0.5f); if (y2r < 0) y2r = 0;
                    int yh = (int)ceilf((g.w - EPS) / s - 0.5f); if (yh > n - 1) yh = n - 1;
                    w2 = xh - x2r + 1; if (w2 < 0) w2 = 0;
                    h2 = yh - y2r + 1; if (h2 < 0) h2 = 0;
                }
                int n0 = w0 * h0, n01 = n0 + w1 * h1, n012 = n01 + w2 * h2;
                int N = n012 + TOPK;               // <= ~583 + 13 <= 640
                float rw0 = __builtin_amdgcn_rcpf((float)w0);
                float rw1 = __builtin_amdgcn_rcpf((float)w1);
                float rw2 = __builtin_amdgcn_rcpf((float)w2);

                // pass A: addresses only (branchy, no loads)
                int aarr[10]; float axv[10], ayv[10];
                unsigned validm = 0;
                #pragma unroll
                for (int j = 0; j < 10; ++j) {
                    aarr[j] = 0; axv[j] = 0.f; ayv[j] = 0.f;
                    int c = lane + j * 64;
                    if (c < N) {
                        int a; float ax, ay; bool dup = false;
                        if (c < n0) {
                            int iy, ix; fdivmod(c, w0, rw0, iy, ix);
                            iy += y0; ix += x0;
                            a = iy * 80 + ix; ax = (ix + 0.5f) * 8.f; ay = (iy + 0.5f) * 8.f;
                        } else if (c < n01) {
                            int iy, ix; fdivmod(c - n0, w1, rw1, iy, ix);
                            iy += y1r; ix += x1r;
                            a = 6400 + iy * 40 + ix; ax = (ix + 0.5f) * 16.f; ay = (iy + 0.5f) * 16.f;
                        } else if (c < n012) {
                            int iy, ix; fdivmod(c - n01, w2, rw2, iy, ix);
                            iy += y2r; ix += x2r;
                            a = 8000 + iy * 20 + ix; ax = (ix + 0.5f) * 32.f; ay = (iy + 0.5f) * 32.f;
                        } else {
                            a = c - n012;          // supplement: L0 row 0, ix=a
                            ax = (a + 0.5f) * 8.f; ay = 4.0f;
                            dup = (h0 > 0) && (y0 == 0) && (w0 > 0) &&
                                  (x0 <= a) && (a <= x0 + w0 - 1);
                        }
                        if (!dup) { aarr[j] = a; axv[j] = ax; ayv[j] = ay; validm |= 1u << j; }
                    }
                }
                // pass B: all 20 gathers issued back-to-back (a=0 for invalid)
                float4 pv[10]; float sv[10];
                #pragma unroll
                for (int j = 0; j < 10; ++j) {
                    pv[j] = pb[aarr[j]];
                    sv[j] = srow[(size_t)aarr[j] * NC];
                }
                // pass C: values + packed keys
                unsigned long long key[10];
                unsigned insmask = 0;
                #pragma unroll
                for (int j = 0; j < 10; ++j) {
                    key[j] = 0ull;
                    if (validm & (1u << j)) {
                        float ov = iou_xyxy(g, pv[j]);
                        bool ins = fminf(fminf(axv[j] - g.x, ayv[j] - g.y),
                                         fminf(g.z - axv[j], g.w - ayv[j])) > EPS;
                        float o2 = ov * ov;
                        float val = ins ? sv[j] * o2 * o2 * o2 : 0.f;
                        key[j] = ((unsigned long long)__float_as_uint(val) << 32)
                               | (unsigned)(0xFFFFFFFFu - (unsigned)aarr[j]);
                        if (ins) insmask |= (1u << j);
                    }
                }
                // 13 rounds of wave argmax (exact top_k order: value desc, idx asc)
                for (int r = 0; r < TOPK; ++r) {
                    unsigned long long best = 0ull;
                    #pragma unroll
                    for (int j = 0; j < 10; ++j) if (key[j] > best) best = key[j];
                    #pragma unroll
                    for (int off = 32; off >= 1; off >>= 1) {
                        unsigned long long o = __shfl_xor(best, off, 64);
                        if (o > best) best = o;
                    }
                    #pragma unroll
                    for (int j = 0; j < 10; ++j) {
                        if (key[j] == best) {      // unique owner
                            key[j] = 0ull;
                            if ((insmask >> j) & 1u) {
                                int a = (int)(0xFFFFFFFFu - (unsigned)best);
                                atomicAdd(&cm[b * NA + a], (1u << 20) | (unsigned)mm);
                            }
                        }
                    }
                }
            }
        }
    }
    gbar(bar + 0, NBLK);

    // ------------- phase 2: resolution (1 anchor per thread, exact) ----------
    int t = blockIdx.x * 256 + threadIdx.x;    // < BS*NA always (525*256 exact)
    int b = t / NA;
    int idx = 0, fg = 0, lbl;
    float al = 0.f;
    {
        unsigned c = __hip_atomic_load(&cm[t], __ATOMIC_RELAXED,
                                       __HIP_MEMORY_SCOPE_AGENT);
        int cnt = (int)(c >> 20);
        float4 p = ((const float4*)pboxes)[t];
        if (cnt == 1) { idx = (int)(c & 0xFFFFFu); fg = 1; }
        else if (cnt > 1) {
            float best = -1.f; int bmx = 0;
            for (int m = 0; m < NMB; ++m) {
                float ov = iou_xyxy(gb4[b * NMB + m], p);   // L2-resident
                if (ov > best) { best = ov; bmx = m; }
            }
            idx = bmx; fg = 1;
        }
        lbl = glabels[b * NMB + idx];
        if (lbl < 0) lbl = 0;
        float4 gbx = gb4[b * NMB + idx];
        if (fg) {
            float ov = iou_xyxy(gbx, p);
            float sc = scores[(size_t)t * NC + lbl];
            float o2 = ov * ov;
            al = sc * o2 * o2 * o2;            // UNMASKED align (matches ref)
            atomicMax(&posalign[b * NMB + idx], __float_as_uint(al));
            atomicMax(&posover[b * NMB + idx], __float_as_uint(ov));
        }
        out[OUT_LABELS + t] = (float)lbl;      // gather NOT masked by fg (ref)
        ((float4*)(out + OUT_BBOX))[t] = gbx;
        out[OUT_FG + t] = fg ? 1.f : 0.f;
    }
    gbar(bar + 1, NBLK);

    // ------------- phase 3: score rows, block-cooperative coalesced ----------
    __shared__ float s_norm[256];
    __shared__ int   s_lbl[256];
    {
        float norm = 0.f; int plbl = -1;
        if (fg) {
            unsigned pau = __hip_atomic_load(&posalign[b * NMB + idx],
                                             __ATOMIC_RELAXED, __HIP_MEMORY_SCOPE_AGENT);
            unsigned pou = __hip_atomic_load(&posover[b * NMB + idx],
                                             __ATOMIC_RELAXED, __HIP_MEMORY_SCOPE_AGENT);
            norm = al * __uint_as_float(pou) / (__uint_as_float(pau) + EPS);
            plbl = lbl;
        }
        s_norm[threadIdx.x] = norm;
        s_lbl[threadIdx.x] = plbl;
        __syncthreads();
        int base = blockIdx.x * (256 * (NC / 4));
        #pragma unroll
        for (int k = 0; k < NC / 4; ++k) {
            int cidx = threadIdx.x + k * 256;
            int r = cidx / (NC / 4), q = cidx - r * (NC / 4);
            float nv = s_norm[r]; int lv = s_lbl[r];
            int c0 = q * 4;
            f32x4 w;
            w.x = (c0     == lv) ? nv : 0.f;
            w.y = (c0 + 1 == lv) ? nv : 0.f;
            w.z = (c0 + 2 == lv) ? nv : 0.f;
            w.w = (c0 + 3 == lv) ? nv : 0.f;
            ((f32x4*)(out + OUT_SCORES))[base + cidx] = w;
        }
    }
}

extern "C" void kernel_launch(void* const* d_in, const int* in_sizes, int n_in,
                              void* d_out, int out_size, void* d_ws, size_t ws_size,
                              hipStream_t stream) {
    const float* scores  = (const float*)d_in[0];   // [BS,NA,NC]
    const float* pboxes  = (const float*)d_in[1];   // [BS,NA,4]
    const float* gboxes  = (const float*)d_in[3];   // [BS,NMB,4]
    const float* maskgt  = (const float*)d_in[4];   // [BS,NMB,1]
    const int*   glabels = (const int*)d_in[5];     // [BS,NMB,1]
    float* out = (float*)d_out;

    k_init<<<(INIT_VEC + 255) / 256, 256, 0, stream>>>((uint4*)d_ws);
    k_fused<<<NBLK, 256, 0, stream>>>(scores, pboxes, gboxes, maskgt, glabels,
                                      (unsigned int*)d_ws, out);
}

// Round 12
// 93.916 us; speedup vs baseline: 3.4319x; 1.4548x over previous
//
#include <hip/hip_runtime.h>
#include <hip/hip_bf16.h>

#define BS   16
#define NA   8400
#define NMB  100
#define NC   80
#define TOPK 13
#define EPS  1e-9f
#define NBLK 525                              // 525*256 == BS*NA exactly

typedef float f32x4 __attribute__((ext_vector_type(4)));

// output layout (floats): labels [BS,NA] | bboxes [BS,NA,4] | scores [BS,NA,NC] | fg [BS,NA]
#define OUT_LABELS 0
#define OUT_BBOX   (BS * NA)
#define OUT_SCORES (BS * NA * 5)
#define OUT_FG     (BS * NA * 5 + BS * NA * NC)

// ws (u32 units): cm[BS*NA] | posalign[1600] | posover[1600] | cnt0,cnt1 | go[NBLK lines]
#define CM_OFF   0
#define PA_OFF   (BS * NA)                    // 134400
#define PO_OFF   (BS * NA + BS * NMB)         // 136000
#define BAR_OFF  (BS * NA + 2 * BS * NMB)     // 137600: cnt0 @+0, cnt1 @+16
#define GO_OFF   (BAR_OFF + 32)               // go[i] @ GO_OFF + i*16 (64B spacing)
#define INIT_U32 (GO_OFF + NBLK * 16)         // 146032
#define INIT_VEC ((INIT_U32 + 3) / 4)         // 36508

__device__ __forceinline__ float iou_xyxy(float4 g, float4 p) {
    float lx = fmaxf(g.x, p.x), ly = fmaxf(g.y, p.y);
    float rx = fminf(g.z, p.z), ry = fminf(g.w, p.w);
    float w = fmaxf(rx - lx, 0.f), h = fmaxf(ry - ly, 0.f);
    float inter = w * h;
    float ag = (g.z - g.x) * (g.w - g.y);
    float ap = (p.z - p.x) * (p.w - p.y);
    return inter / (ag + ap - inter + EPS);
}

// fast unsigned divide for small c (<4096), w (<128): rcp + correction
__device__ __forceinline__ void fdivmod(int c, int w, float rw, int& q, int& r) {
    q = (int)((float)c * rw);
    r = c - q * w;
    if (r < 0) { q--; r += w; }
    else if (r >= w) { q++; r -= w; }
}

// Central-release grid barrier: arrivals are fire-and-forget atomicAdds;
// ONLY block 0 polls the counter (1 poller, no same-line queueing); release
// fans out to per-block 64B-spaced go lines, each polled by exactly 1 wave.
// All cross-phase data flows through agent-scope atomics (coherence point),
// so no L2 writeback fence is needed; vmcnt(0) drains this wave's atomics.
__device__ __forceinline__ void gbar(unsigned* ws, int which) {
    unsigned* cnt = ws + BAR_OFF + which * 16;
    unsigned* go  = ws + GO_OFF;
    unsigned epoch = (unsigned)(which + 1);
    __syncthreads();
    if (blockIdx.x == 0) {
        if (threadIdx.x == 0) {
            asm volatile("s_waitcnt vmcnt(0)" ::: "memory");
            __hip_atomic_fetch_add(cnt, 1u, __ATOMIC_RELAXED,
                                   __HIP_MEMORY_SCOPE_AGENT);
            while (__hip_atomic_load(cnt, __ATOMIC_RELAXED,
                                     __HIP_MEMORY_SCOPE_AGENT) < (unsigned)NBLK)
                __builtin_amdgcn_s_sleep(8);
        }
        __syncthreads();                       // all blocks arrived
        for (int i = threadIdx.x; i < NBLK; i += 256)
            __hip_atomic_store(&go[i * 16], epoch, __ATOMIC_RELAXED,
                               __HIP_MEMORY_SCOPE_AGENT);
    } else {
        if (threadIdx.x == 0) {
            asm volatile("s_waitcnt vmcnt(0)" ::: "memory");
            __hip_atomic_fetch_add(cnt, 1u, __ATOMIC_RELAXED,
                                   __HIP_MEMORY_SCOPE_AGENT);
            while (__hip_atomic_load(&go[blockIdx.x * 16], __ATOMIC_RELAXED,
                                     __HIP_MEMORY_SCOPE_AGENT) < epoch)
                __builtin_amdgcn_s_sleep(8);
        }
        __syncthreads();
    }
    asm volatile("" ::: "memory");             // compiler fence only
}

// Zero cm + posalign + posover + barrier counters + go lines (584 KB).
__global__ __launch_bounds__(256) void k_init(uint4* __restrict__ ws) {
    int t = blockIdx.x * 256 + threadIdx.x;
    if (t < INIT_VEC) ws[t] = make_uint4(0u, 0u, 0u, 0u);
}

// Persistent fused kernel: phase1 topk | bar | phase2 resolve | bar | phase3
// score. 525 blocks x 256 threads; launch_bounds(256,4) -> all co-resident.
__global__ __launch_bounds__(256, 4) void k_fused(
        const float* __restrict__ scores, const float* __restrict__ pboxes,
        const float* __restrict__ gboxes, const float* __restrict__ maskgt,
        const int* __restrict__ glabels,
        unsigned int* __restrict__ ws, float* __restrict__ out) {
    unsigned int* cm       = ws + CM_OFF;
    unsigned int* posalign = ws + PA_OFF;
    unsigned int* posover  = ws + PO_OFF;
    const float4* gb4 = (const float4*)gboxes;

    // ---------------- phase 1: top-k per GT (one wave per GT) ----------------
    {
        int w = blockIdx.x * 4 + (threadIdx.x >> 6);
        if (w < BS * NMB) {
            int bm = (w & 7) * 200 + (w >> 3);     // XCD spread
            float mg = maskgt[bm];
            float4 g = gb4[bm];
            int lbl = glabels[bm];
            if (mg > 0.f) {
                int b = bm / NMB, mm = bm - b * NMB;
                int lane = threadIdx.x & 63;
                const float* srow = scores + (size_t)b * NA * NC + lbl;
                const float4* pb = (const float4*)pboxes + (size_t)b * NA;

                // padded per-level index ranges; ins test is the exact filter
                int x0, y0, w0, h0, x1r, y1r, w1, h1, x2r, y2r, w2, h2;
                {
                    float s = 8.f; int n = 80;
                    x0 = (int)floorf((g.x + EPS) / s - 0.5f); if (x0 < 0) x0 = 0;
                    int xh = (int)ceilf((g.z - EPS) / s - 0.5f); if (xh > n - 1) xh = n - 1;
                    y0 = (int)floorf((g.y + EPS) / s - 0.5f); if (y0 < 0) y0 = 0;
                    int yh = (int)ceilf((g.w - EPS) / s - 0.5f); if (yh > n - 1) yh = n - 1;
                    w0 = xh - x0 + 1; if (w0 < 0) w0 = 0;
                    h0 = yh - y0 + 1; if (h0 < 0) h0 = 0;
                }
                {
                    float s = 16.f; int n = 40;
                    x1r = (int)floorf((g.x + EPS) / s - 0.5f); if (x1r < 0) x1r = 0;
                    int xh = (int)ceilf((g.z - EPS) / s - 0.5f); if (xh > n - 1) xh = n - 1;
                    y1r = (int)floorf((g.y + EPS) / s - 0.5f); if (y1r < 0) y1r = 0;
                    int yh = (int)ceilf((g.w - EPS) / s - 0.5f); if (yh > n - 1) yh = n - 1;
                    w1 = xh - x1r + 1; if (w1 < 0) w1 = 0;
                    h1 = yh - y1r + 1; if (h1 < 0) h1 = 0;
                }
                {
                    float s = 32.f; int n = 20;
                    x2r = (int)floorf((g.x + EPS) / s - 0.5f); if (x2r < 0) x2r = 0;
                    int xh = (int)ceilf((g.z - EPS) / s - 0.5f); if (xh > n - 1) xh = n - 1;
                    y2r = (int)floorf((g.y + EPS) / s - 0.5f); if (y2r < 0) y2r = 0;
                    int yh = (int)ceilf((g.w - EPS) / s - 0.5f); if (yh > n - 1) yh = n - 1;
                    w2 = xh - x2r + 1; if (w2 < 0) w2 = 0;
                    h2 = yh - y2r + 1; if (h2 < 0) h2 = 0;
                }
                int n0 = w0 * h0, n01 = n0 + w1 * h1, n012 = n01 + w2 * h2;
                int N = n012 + TOPK;               // <= ~583 + 13 <= 640
                float rw0 = __builtin_amdgcn_rcpf((float)w0);
                float rw1 = __builtin_amdgcn_rcpf((float)w1);
                float rw2 = __builtin_amdgcn_rcpf((float)w2);

                // pass A: addresses only (branchy, no loads)
                int aarr[10]; float axv[10], ayv[10];
                unsigned validm = 0;
                #pragma unroll
                for (int j = 0; j < 10; ++j) {
                    aarr[j] = 0; axv[j] = 0.f; ayv[j] = 0.f;
                    int c = lane + j * 64;
                    if (c < N) {
                        int a; float ax, ay; bool dup = false;
                        if (c < n0) {
                            int iy, ix; fdivmod(c, w0, rw0, iy, ix);
                            iy += y0; ix += x0;
                            a = iy * 80 + ix; ax = (ix + 0.5f) * 8.f; ay = (iy + 0.5f) * 8.f;
                        } else if (c < n01) {
                            int iy, ix; fdivmod(c - n0, w1, rw1, iy, ix);
                            iy += y1r; ix += x1r;
                            a = 6400 + iy * 40 + ix; ax = (ix + 0.5f) * 16.f; ay = (iy + 0.5f) * 16.f;
                        } else if (c < n012) {
                            int iy, ix; fdivmod(c - n01, w2, rw2, iy, ix);
                            iy += y2r; ix += x2r;
                            a = 8000 + iy * 20 + ix; ax = (ix + 0.5f) * 32.f; ay = (iy + 0.5f) * 32.f;
                        } else {
                            a = c - n012;          // supplement: L0 row 0, ix=a
                            ax = (a + 0.5f) * 8.f; ay = 4.0f;
                            dup = (h0 > 0) && (y0 == 0) && (w0 > 0) &&
                                  (x0 <= a) && (a <= x0 + w0 - 1);
                        }
                        if (!dup) { aarr[j] = a; axv[j] = ax; ayv[j] = ay; validm |= 1u << j; }
                    }
                }
                // pass B: all 20 gathers issued back-to-back (a=0 for invalid)
                float4 pv[10]; float sv[10];
                #pragma unroll
                for (int j = 0; j < 10; ++j) {
                    pv[j] = pb[aarr[j]];
                    sv[j] = srow[(size_t)aarr[j] * NC];
                }
                // pass C: values + packed keys
                unsigned long long key[10];
                unsigned insmask = 0;
                #pragma unroll
                for (int j = 0; j < 10; ++j) {
                    key[j] = 0ull;
                    if (validm & (1u << j)) {
                        float ov = iou_xyxy(g, pv[j]);
                        bool ins = fminf(fminf(axv[j] - g.x, ayv[j] - g.y),
                                         fminf(g.z - axv[j], g.w - ayv[j])) > EPS;
                        float o2 = ov * ov;
                        float val = ins ? sv[j] * o2 * o2 * o2 : 0.f;
                        key[j] = ((unsigned long long)__float_as_uint(val) << 32)
                               | (unsigned)(0xFFFFFFFFu - (unsigned)aarr[j]);
                        if (ins) insmask |= (1u << j);
                    }
                }
                // 13 rounds of wave argmax (exact top_k order: value desc, idx asc)
                for (int r = 0; r < TOPK; ++r) {
                    unsigned long long best = 0ull;
                    #pragma unroll
                    for (int j = 0; j < 10; ++j) if (key[j] > best) best = key[j];
                    #pragma unroll
                    for (int off = 32; off >= 1; off >>= 1) {
                        unsigned long long o = __shfl_xor(best, off, 64);
                        if (o > best) best = o;
                    }
                    #pragma unroll
                    for (int j = 0; j < 10; ++j) {
                        if (key[j] == best) {      // unique owner
                            key[j] = 0ull;
                            if ((insmask >> j) & 1u) {
                                int a = (int)(0xFFFFFFFFu - (unsigned)best);
                                atomicAdd(&cm[b * NA + a], (1u << 20) | (unsigned)mm);
                            }
                        }
                    }
                }
            }
        }
    }
    gbar(ws, 0);

    // ------------- phase 2: resolution (1 anchor per thread, exact) ----------
    int t = blockIdx.x * 256 + threadIdx.x;    // < BS*NA always (525*256 exact)
    int b = t / NA;
    int idx = 0, fg = 0, lbl;
    float al = 0.f;
    {
        unsigned c = __hip_atomic_load(&cm[t], __ATOMIC_RELAXED,
                                       __HIP_MEMORY_SCOPE_AGENT);
        int cnt = (int)(c >> 20);
        float4 p = ((const float4*)pboxes)[t];
        if (cnt == 1) { idx = (int)(c & 0xFFFFFu); fg = 1; }
        else if (cnt > 1) {
            float best = -1.f; int bmx = 0;
            for (int m = 0; m < NMB; ++m) {
                float ov = iou_xyxy(gb4[b * NMB + m], p);   // L2-resident
                if (ov > best) { best = ov; bmx = m; }
            }
            idx = bmx; fg = 1;
        }
        lbl = glabels[b * NMB + idx];
        if (lbl < 0) lbl = 0;
        float4 gbx = gb4[b * NMB + idx];
        if (fg) {
            float ov = iou_xyxy(gbx, p);
            float sc = scores[(size_t)t * NC + lbl];
            float o2 = ov * ov;
            al = sc * o2 * o2 * o2;            // UNMASKED align (matches ref)
            atomicMax(&posalign[b * NMB + idx], __float_as_uint(al));
            atomicMax(&posover[b * NMB + idx], __float_as_uint(ov));
        }
        out[OUT_LABELS + t] = (float)lbl;      // gather NOT masked by fg (ref)
        ((float4*)(out + OUT_BBOX))[t] = gbx;
        out[OUT_FG + t] = fg ? 1.f : 0.f;
    }
    gbar(ws, 1);

    // ------------- phase 3: score rows, block-cooperative coalesced ----------
    __shared__ float s_norm[256];
    __shared__ int   s_lbl[256];
    {
        float norm = 0.f; int plbl = -1;
        if (fg) {
            unsigned pau = __hip_atomic_load(&posalign[b * NMB + idx],
                                             __ATOMIC_RELAXED, __HIP_MEMORY_SCOPE_AGENT);
            unsigned pou = __hip_atomic_load(&posover[b * NMB + idx],
                                             __ATOMIC_RELAXED, __HIP_MEMORY_SCOPE_AGENT);
            norm = al * __uint_as_float(pou) / (__uint_as_float(pau) + EPS);
            plbl = lbl;
        }
        s_norm[threadIdx.x] = norm;
        s_lbl[threadIdx.x] = plbl;
        __syncthreads();
        int base = blockIdx.x * (256 * (NC / 4));
        #pragma unroll
        for (int k = 0; k < NC / 4; ++k) {
            int cidx = threadIdx.x + k * 256;
            int r = cidx / (NC / 4), q = cidx - r * (NC / 4);
            float nv = s_norm[r]; int lv = s_lbl[r];
            int c0 = q * 4;
            f32x4 w;
            w.x = (c0     == lv) ? nv : 0.f;
            w.y = (c0 + 1 == lv) ? nv : 0.f;
            w.z = (c0 + 2 == lv) ? nv : 0.f;
            w.w = (c0 + 3 == lv) ? nv : 0.f;
            ((f32x4*)(out + OUT_SCORES))[base + cidx] = w;
        }
    }
}

extern "C" void kernel_launch(void* const* d_in, const int* in_sizes, int n_in,
                              void* d_out, int out_size, void* d_ws, size_t ws_size,
                              hipStream_t stream) {
    const float* scores  = (const float*)d_in[0];   // [BS,NA,NC]
    const float* pboxes  = (const float*)d_in[1];   // [BS,NA,4]
    const float* gboxes  = (const float*)d_in[3];   // [BS,NMB,4]
    const float* maskgt  = (const float*)d_in[4];   // [BS,NMB,1]
    const int*   glabels = (const int*)d_in[5];     // [BS,NMB,1]
    float* out = (float*)d_out;

    k_init<<<(INIT_VEC + 255) / 256, 256, 0, stream>>>((uint4*)d_ws);
    k_fused<<<NBLK, 256, 0, stream>>>(scores, pboxes, gboxes, maskgt, glabels,
                                      (unsigned int*)d_ws, out);
}

// Round 13
// 74.099 us; speedup vs baseline: 4.3498x; 1.2674x over previous
//
#include <hip/hip_runtime.h>
#include <hip/hip_bf16.h>

#define BS   16
#define NA   8400
#define NMB  100
#define NC   80
#define TOPK 13
#define EPS  1e-9f
#define NBLK 525                              // 525*256 == BS*NA exactly

typedef float f32x4 __attribute__((ext_vector_type(4)));

// output layout (floats): labels [BS,NA] | bboxes [BS,NA,4] | scores [BS,NA,NC] | fg [BS,NA]
#define OUT_LABELS 0
#define OUT_BBOX   (BS * NA)
#define OUT_SCORES (BS * NA * 5)
#define OUT_FG     (BS * NA * 5 + BS * NA * NC)

// ws (u32 units): cm[BS*NA] | posalign[1600] | posover[1600] |
//   arrival counters: 2 barriers x 8 lines x 16 u32 | go[NBLK] x 16 u32
#define CM_OFF   0
#define PA_OFF   (BS * NA)                    // 134400
#define PO_OFF   (BS * NA + BS * NMB)         // 136000
#define BAR_OFF  (BS * NA + 2 * BS * NMB)     // 137600
#define GO_OFF   (BAR_OFF + 256)              // 137856
#define INIT_U32 (GO_OFF + NBLK * 16)         // 146256
#define INIT_VEC ((INIT_U32 + 3) / 4)         // 36564

__device__ __forceinline__ float iou_xyxy(float4 g, float4 p) {
    float lx = fmaxf(g.x, p.x), ly = fmaxf(g.y, p.y);
    float rx = fminf(g.z, p.z), ry = fminf(g.w, p.w);
    float w = fmaxf(rx - lx, 0.f), h = fmaxf(ry - ly, 0.f);
    float inter = w * h;
    float ag = (g.z - g.x) * (g.w - g.y);
    float ap = (p.z - p.x) * (p.w - p.y);
    return inter / (ag + ap - inter + EPS);
}

// fast unsigned divide for small c (<4096), w (<128): rcp + correction
__device__ __forceinline__ void fdivmod(int c, int w, float rw, int& q, int& r) {
    q = (int)((float)c * rw);
    r = c - q * w;
    if (r < 0) { q--; r += w; }
    else if (r >= w) { q++; r -= w; }
}

// Central-release grid barrier, 8-way-split arrivals:
//  - arrival: fire-and-forget relaxed atomicAdd to cnt[blockIdx&7] (max ~66
//    RMWs per line instead of 525 -> no deep same-line serialization)
//  - ONLY block 0 polls (sums the 8 lines); release fans out to per-block
//    64B-spaced go lines, each polled by exactly 1 wave.
// All cross-phase data flows through agent-scope atomics (coherence point),
// so no L2-writeback fence is needed; vmcnt(0) drains this wave's atomics.
__device__ __forceinline__ void gbar(unsigned* ws, int which) {
    unsigned* cnt = ws + BAR_OFF + which * 128;
    unsigned* go  = ws + GO_OFF;
    unsigned epoch = (unsigned)(which + 1);
    __syncthreads();
    if (threadIdx.x == 0) {
        asm volatile("s_waitcnt vmcnt(0)" ::: "memory");
        __hip_atomic_fetch_add(&cnt[(blockIdx.x & 7) * 16], 1u,
                               __ATOMIC_RELAXED, __HIP_MEMORY_SCOPE_AGENT);
    }
    if (blockIdx.x == 0) {
        if (threadIdx.x == 0) {
            unsigned s;
            do {
                __builtin_amdgcn_s_sleep(8);
                s = 0;
                #pragma unroll
                for (int i = 0; i < 8; ++i)
                    s += __hip_atomic_load(&cnt[i * 16], __ATOMIC_RELAXED,
                                           __HIP_MEMORY_SCOPE_AGENT);
            } while (s < (unsigned)NBLK);
        }
        __syncthreads();                       // all blocks arrived
        for (int i = threadIdx.x; i < NBLK; i += 256)
            __hip_atomic_store(&go[i * 16], epoch, __ATOMIC_RELAXED,
                               __HIP_MEMORY_SCOPE_AGENT);
    } else {
        if (threadIdx.x == 0) {
            while (__hip_atomic_load(&go[blockIdx.x * 16], __ATOMIC_RELAXED,
                                     __HIP_MEMORY_SCOPE_AGENT) < epoch)
                __builtin_amdgcn_s_sleep(8);
        }
        __syncthreads();
    }
    asm volatile("" ::: "memory");             // compiler fence only
}

// Zero cm + posalign + posover + barrier counters + go lines (585 KB).
__global__ __launch_bounds__(256) void k_init(uint4* __restrict__ ws) {
    int t = blockIdx.x * 256 + threadIdx.x;
    if (t < INIT_VEC) ws[t] = make_uint4(0u, 0u, 0u, 0u);
}

// Persistent fused kernel: phase1 topk | bar | phase2 resolve | bar | phase3
// score. 525 blocks x 256 threads; launch_bounds(256,3) -> VGPR budget ~170
// (NO spills of phase-1's ~100-reg live set -- (256,4) forced 64 VGPRs and
// spilled key[]/pv[]/sv[] to scratch: 3.3x write amplification in R11/R12),
// 3 blocks/CU capacity -> 768 slots >= 525 -> all co-resident.
__global__ __launch_bounds__(256, 3) void k_fused(
        const float* __restrict__ scores, const float* __restrict__ pboxes,
        const float* __restrict__ gboxes, const float* __restrict__ maskgt,
        const int* __restrict__ glabels,
        unsigned int* __restrict__ ws, float* __restrict__ out) {
    unsigned int* cm       = ws + CM_OFF;
    unsigned int* posalign = ws + PA_OFF;
    unsigned int* posover  = ws + PO_OFF;
    const float4* gb4 = (const float4*)gboxes;

    // ---------------- phase 1: top-k per GT (one wave per GT) ----------------
    {
        int w = blockIdx.x * 4 + (threadIdx.x >> 6);
        if (w < BS * NMB) {
            int bm = (w & 7) * 200 + (w >> 3);     // XCD spread
            float mg = maskgt[bm];
            float4 g = gb4[bm];
            int lbl = glabels[bm];
            if (mg > 0.f) {
                int b = bm / NMB, mm = bm - b * NMB;
                int lane = threadIdx.x & 63;
                const float* srow = scores + (size_t)b * NA * NC + lbl;
                const float4* pb = (const float4*)pboxes + (size_t)b * NA;

                // padded per-level index ranges; ins test is the exact filter
                int x0, y0, w0, h0, x1r, y1r, w1, h1, x2r, y2r, w2, h2;
                {
                    float s = 8.f; int n = 80;
                    x0 = (int)floorf((g.x + EPS) / s - 0.5f); if (x0 < 0) x0 = 0;
                    int xh = (int)ceilf((g.z - EPS) / s - 0.5f); if (xh > n - 1) xh = n - 1;
                    y0 = (int)floorf((g.y + EPS) / s - 0.5f); if (y0 < 0) y0 = 0;
                    int yh = (int)ceilf((g.w - EPS) / s - 0.5f); if (yh > n - 1) yh = n - 1;
                    w0 = xh - x0 + 1; if (w0 < 0) w0 = 0;
                    h0 = yh - y0 + 1; if (h0 < 0) h0 = 0;
                }
                {
                    float s = 16.f; int n = 40;
                    x1r = (int)floorf((g.x + EPS) / s - 0.5f); if (x1r < 0) x1r = 0;
                    int xh = (int)ceilf((g.z - EPS) / s - 0.5f); if (xh > n - 1) xh = n - 1;
                    y1r = (int)floorf((g.y + EPS) / s - 0.5f); if (y1r < 0) y1r = 0;
                    int yh = (int)ceilf((g.w - EPS) / s - 0.5f); if (yh > n - 1) yh = n - 1;
                    w1 = xh - x1r + 1; if (w1 < 0) w1 = 0;
                    h1 = yh - y1r + 1; if (h1 < 0) h1 = 0;
                }
                {
                    float s = 32.f; int n = 20;
                    x2r = (int)floorf((g.x + EPS) / s - 0.5f); if (x2r < 0) x2r = 0;
                    int xh = (int)ceilf((g.z - EPS) / s - 0.5f); if (xh > n - 1) xh = n - 1;
                    y2r = (int)floorf((g.y + EPS) / s - 0.5f); if (y2r < 0) y2r = 0;
                    int yh = (int)ceilf((g.w - EPS) / s - 0.5f); if (yh > n - 1) yh = n - 1;
                    w2 = xh - x2r + 1; if (w2 < 0) w2 = 0;
                    h2 = yh - y2r + 1; if (h2 < 0) h2 = 0;
                }
                int n0 = w0 * h0, n01 = n0 + w1 * h1, n012 = n01 + w2 * h2;
                int N = n012 + TOPK;               // <= ~583 + 13 <= 640
                float rw0 = __builtin_amdgcn_rcpf((float)w0);
                float rw1 = __builtin_amdgcn_rcpf((float)w1);
                float rw2 = __builtin_amdgcn_rcpf((float)w2);

                // pass A: addresses only (branchy, no loads)
                int aarr[10]; float axv[10], ayv[10];
                unsigned validm = 0;
                #pragma unroll
                for (int j = 0; j < 10; ++j) {
                    aarr[j] = 0; axv[j] = 0.f; ayv[j] = 0.f;
                    int c = lane + j * 64;
                    if (c < N) {
                        int a; float ax, ay; bool dup = false;
                        if (c < n0) {
                            int iy, ix; fdivmod(c, w0, rw0, iy, ix);
                            iy += y0; ix += x0;
                            a = iy * 80 + ix; ax = (ix + 0.5f) * 8.f; ay = (iy + 0.5f) * 8.f;
                        } else if (c < n01) {
                            int iy, ix; fdivmod(c - n0, w1, rw1, iy, ix);
                            iy += y1r; ix += x1r;
                            a = 6400 + iy * 40 + ix; ax = (ix + 0.5f) * 16.f; ay = (iy + 0.5f) * 16.f;
                        } else if (c < n012) {
                            int iy, ix; fdivmod(c - n01, w2, rw2, iy, ix);
                            iy += y2r; ix += x2r;
                            a = 8000 + iy * 20 + ix; ax = (ix + 0.5f) * 32.f; ay = (iy + 0.5f) * 32.f;
                        } else {
                            a = c - n012;          // supplement: L0 row 0, ix=a
                            ax = (a + 0.5f) * 8.f; ay = 4.0f;
                            dup = (h0 > 0) && (y0 == 0) && (w0 > 0) &&
                                  (x0 <= a) && (a <= x0 + w0 - 1);
                        }
                        if (!dup) { aarr[j] = a; axv[j] = ax; ayv[j] = ay; validm |= 1u << j; }
                    }
                }
                // pass B: all 20 gathers issued back-to-back (a=0 for invalid)
                float4 pv[10]; float sv[10];
                #pragma unroll
                for (int j = 0; j < 10; ++j) {
                    pv[j] = pb[aarr[j]];
                    sv[j] = srow[(size_t)aarr[j] * NC];
                }
                // pass C: values + packed keys
                unsigned long long key[10];
                unsigned insmask = 0;
                #pragma unroll
                for (int j = 0; j < 10; ++j) {
                    key[j] = 0ull;
                    if (validm & (1u << j)) {
                        float ov = iou_xyxy(g, pv[j]);
                        bool ins = fminf(fminf(axv[j] - g.x, ayv[j] - g.y),
                                         fminf(g.z - axv[j], g.w - ayv[j])) > EPS;
                        float o2 = ov * ov;
                        float val = ins ? sv[j] * o2 * o2 * o2 : 0.f;
                        key[j] = ((unsigned long long)__float_as_uint(val) << 32)
                               | (unsigned)(0xFFFFFFFFu - (unsigned)aarr[j]);
                        if (ins) insmask |= (1u << j);
                    }
                }
                // 13 rounds of wave argmax (exact top_k order: value desc, idx asc)
                for (int r = 0; r < TOPK; ++r) {
                    unsigned long long best = 0ull;
                    #pragma unroll
                    for (int j = 0; j < 10; ++j) if (key[j] > best) best = key[j];
                    #pragma unroll
                    for (int off = 32; off >= 1; off >>= 1) {
                        unsigned long long o = __shfl_xor(best, off, 64);
                        if (o > best) best = o;
                    }
                    #pragma unroll
                    for (int j = 0; j < 10; ++j) {
                        if (key[j] == best) {      // unique owner
                            key[j] = 0ull;
                            if ((insmask >> j) & 1u) {
                                int a = (int)(0xFFFFFFFFu - (unsigned)best);
                                atomicAdd(&cm[b * NA + a], (1u << 20) | (unsigned)mm);
                            }
                        }
                    }
                }
            }
        }
    }
    gbar(ws, 0);

    // ------------- phase 2: resolution (1 anchor per thread, exact) ----------
    int t = blockIdx.x * 256 + threadIdx.x;    // < BS*NA always (525*256 exact)
    int b = t / NA;
    int idx = 0, fg = 0, lbl;
    float al = 0.f;
    {
        unsigned c = __hip_atomic_load(&cm[t], __ATOMIC_RELAXED,
                                       __HIP_MEMORY_SCOPE_AGENT);
        int cnt = (int)(c >> 20);
        float4 p = ((const float4*)pboxes)[t];
        if (cnt == 1) { idx = (int)(c & 0xFFFFFu); fg = 1; }
        else if (cnt > 1) {
            float best = -1.f; int bmx = 0;
            for (int m = 0; m < NMB; ++m) {
                float ov = iou_xyxy(gb4[b * NMB + m], p);   // L2-resident
                if (ov > best) { best = ov; bmx = m; }
            }
            idx = bmx; fg = 1;
        }
        lbl = glabels[b * NMB + idx];
        if (lbl < 0) lbl = 0;
        float4 gbx = gb4[b * NMB + idx];
        if (fg) {
            float ov = iou_xyxy(gbx, p);
            float sc = scores[(size_t)t * NC + lbl];
            float o2 = ov * ov;
            al = sc * o2 * o2 * o2;            // UNMASKED align (matches ref)
            atomicMax(&posalign[b * NMB + idx], __float_as_uint(al));
            atomicMax(&posover[b * NMB + idx], __float_as_uint(ov));
        }
        out[OUT_LABELS + t] = (float)lbl;      // gather NOT masked by fg (ref)
        ((float4*)(out + OUT_BBOX))[t] = gbx;
        out[OUT_FG + t] = fg ? 1.f : 0.f;
    }
    gbar(ws, 1);

    // ------------- phase 3: score rows, block-cooperative coalesced ----------
    __shared__ float s_norm[256];
    __shared__ int   s_lbl[256];
    {
        float norm = 0.f; int plbl = -1;
        if (fg) {
            unsigned pau = __hip_atomic_load(&posalign[b * NMB + idx],
                                             __ATOMIC_RELAXED, __HIP_MEMORY_SCOPE_AGENT);
            unsigned pou = __hip_atomic_load(&posover[b * NMB + idx],
                                             __ATOMIC_RELAXED, __HIP_MEMORY_SCOPE_AGENT);
            norm = al * __uint_as_float(pou) / (__uint_as_float(pau) + EPS);
            plbl = lbl;
        }
        s_norm[threadIdx.x] = norm;
        s_lbl[threadIdx.x] = plbl;
        __syncthreads();
        int base = blockIdx.x * (256 * (NC / 4));
        #pragma unroll
        for (int k = 0; k < NC / 4; ++k) {
            int cidx = threadIdx.x + k * 256;
            int r = cidx / (NC / 4), q = cidx - r * (NC / 4);
            float nv = s_norm[r]; int lv = s_lbl[r];
            int c0 = q * 4;
            f32x4 w;
            w.x = (c0     == lv) ? nv : 0.f;
            w.y = (c0 + 1 == lv) ? nv : 0.f;
            w.z = (c0 + 2 == lv) ? nv : 0.f;
            w.w = (c0 + 3 == lv) ? nv : 0.f;
            ((f32x4*)(out + OUT_SCORES))[base + cidx] = w;
        }
    }
}

extern "C" void kernel_launch(void* const* d_in, const int* in_sizes, int n_in,
                              void* d_out, int out_size, void* d_ws, size_t ws_size,
                              hipStream_t stream) {
    const float* scores  = (const float*)d_in[0];   // [BS,NA,NC]
    const float* pboxes  = (const float*)d_in[1];   // [BS,NA,4]
    const float* gboxes  = (const float*)d_in[3];   // [BS,NMB,4]
    const float* maskgt  = (const float*)d_in[4];   // [BS,NMB,1]
    const int*   glabels = (const int*)d_in[5];     // [BS,NMB,1]
    float* out = (float*)d_out;

    k_init<<<(INIT_VEC + 255) / 256, 256, 0, stream>>>((uint4*)d_ws);
    k_fused<<<NBLK, 256, 0, stream>>>(scores, pboxes, gboxes, maskgt, glabels,
                                      (unsigned int*)d_ws, out);
}

// Round 14
// 73.929 us; speedup vs baseline: 4.3598x; 1.0023x over previous
//
#include <hip/hip_runtime.h>
#include <hip/hip_bf16.h>

#define BS   16
#define NA   8400
#define NMB  100
#define NC   80
#define TOPK 13
#define EPS  1e-9f
#define NBLK 525                              // 525*256 == BS*NA exactly

typedef float f32x4 __attribute__((ext_vector_type(4)));

// output layout (floats): labels [BS,NA] | bboxes [BS,NA,4] | scores [BS,NA,NC] | fg [BS,NA]
#define OUT_LABELS 0
#define OUT_BBOX   (BS * NA)
#define OUT_SCORES (BS * NA * 5)
#define OUT_FG     (BS * NA * 5 + BS * NA * NC)

// ws (u32 units): cm[BS*NA] | posalign[1600] | posover[1600] |
//   arrive[NBLK] x 16 u32 (64B-spaced) | go[NBLK] x 16 u32
#define CM_OFF   0
#define PA_OFF   (BS * NA)                    // 134400
#define PO_OFF   (BS * NA + BS * NMB)         // 136000
#define ARR_OFF  (BS * NA + 2 * BS * NMB)     // 137600
#define GO_OFF   (ARR_OFF + NBLK * 16)        // 146000
#define INIT_U32 (GO_OFF + NBLK * 16)         // 154400
#define INIT_VEC (INIT_U32 / 4)               // 38600

__device__ __forceinline__ float iou_xyxy(float4 g, float4 p) {
    float lx = fmaxf(g.x, p.x), ly = fmaxf(g.y, p.y);
    float rx = fminf(g.z, p.z), ry = fminf(g.w, p.w);
    float w = fmaxf(rx - lx, 0.f), h = fmaxf(ry - ly, 0.f);
    float inter = w * h;
    float ag = (g.z - g.x) * (g.w - g.y);
    float ap = (p.z - p.x) * (p.w - p.y);
    return inter / (ag + ap - inter + EPS);
}

// fast unsigned divide for small c (<4096), w (<128): rcp + correction
__device__ __forceinline__ void fdivmod(int c, int w, float rw, int& q, int& r) {
    q = (int)((float)c * rw);
    r = c - q * w;
    if (r < 0) { q--; r += w; }
    else if (r >= w) { q++; r -= w; }
}

// Store-arrival grid barrier -- ZERO atomic RMWs (the 8-way atomicAdd arrival
// still serialized ~66-deep per line at the MALL: ~20-25us/barrier in R13).
//  - arrival: each block STORES epoch to its own 64B arrive line
//  - block 0's 256 threads sweep the 525 lines in parallel (<=3 each)
//  - release: per-block 64B go lines, 1 poller per line
// __syncthreads() at entry drains all the block's stores (compiler emits full
// waitcnt before s_barrier), so arrive-store ordering is guaranteed.
__device__ __forceinline__ void gbar(unsigned* ws, int which) {
    unsigned* arrive = ws + ARR_OFF;
    unsigned* go     = ws + GO_OFF;
    unsigned epoch = (unsigned)(which + 1);
    __syncthreads();
    if (blockIdx.x == 0) {
        if (threadIdx.x == 0)
            __hip_atomic_store(&arrive[0], epoch, __ATOMIC_RELAXED,
                               __HIP_MEMORY_SCOPE_AGENT);
        for (int i = threadIdx.x; i < NBLK; i += 256) {
            while (__hip_atomic_load(&arrive[i * 16], __ATOMIC_RELAXED,
                                     __HIP_MEMORY_SCOPE_AGENT) < epoch)
                __builtin_amdgcn_s_sleep(8);
        }
        __syncthreads();                       // all 525 arrived
        for (int i = threadIdx.x; i < NBLK; i += 256)
            __hip_atomic_store(&go[i * 16], epoch, __ATOMIC_RELAXED,
                               __HIP_MEMORY_SCOPE_AGENT);
    } else {
        if (threadIdx.x == 0) {
            __hip_atomic_store(&arrive[blockIdx.x * 16], epoch,
                               __ATOMIC_RELAXED, __HIP_MEMORY_SCOPE_AGENT);
            while (__hip_atomic_load(&go[blockIdx.x * 16], __ATOMIC_RELAXED,
                                     __HIP_MEMORY_SCOPE_AGENT) < epoch)
                __builtin_amdgcn_s_sleep(8);
        }
        __syncthreads();
    }
    asm volatile("" ::: "memory");             // compiler fence only
}

// Zero cm + posalign + posover + arrive + go lines (618 KB).
__global__ __launch_bounds__(256) void k_init(uint4* __restrict__ ws) {
    int t = blockIdx.x * 256 + threadIdx.x;
    if (t < INIT_VEC) ws[t] = make_uint4(0u, 0u, 0u, 0u);
}

// Persistent fused kernel: phase1 topk | bar | phase2 resolve | bar | phase3
// score. 525 blocks x 256 threads; launch_bounds(256,3) -> VGPR budget ~170
// (no forced spill of phase-1's live set; (256,4)'s 64-VGPR cap caused 3.3x
// write amplification in R11/R12). Post-barrier reads of cm/posalign/posover
// use PLAIN loads (L2-cacheable): k_init's end-of-dispatch flush cleans L2,
// phase-1/2 atomics run at the coherence point, barrier orders them.
__global__ __launch_bounds__(256, 3) void k_fused(
        const float* __restrict__ scores, const float* __restrict__ pboxes,
        const float* __restrict__ gboxes, const float* __restrict__ maskgt,
        const int* __restrict__ glabels,
        unsigned int* __restrict__ ws, float* __restrict__ out) {
    unsigned int* cm       = ws + CM_OFF;
    unsigned int* posalign = ws + PA_OFF;
    unsigned int* posover  = ws + PO_OFF;
    const float4* gb4 = (const float4*)gboxes;

    // ---------------- phase 1: top-k per GT (one wave per GT) ----------------
    {
        int w = blockIdx.x * 4 + (threadIdx.x >> 6);
        if (w < BS * NMB) {
            int bm = (w & 7) * 200 + (w >> 3);     // XCD spread
            float mg = maskgt[bm];
            float4 g = gb4[bm];
            int lbl = glabels[bm];
            if (mg > 0.f) {
                int b = bm / NMB, mm = bm - b * NMB;
                int lane = threadIdx.x & 63;
                const float* srow = scores + (size_t)b * NA * NC + lbl;
                const float4* pb = (const float4*)pboxes + (size_t)b * NA;

                // padded per-level index ranges; ins test is the exact filter
                int x0, y0, w0, h0, x1r, y1r, w1, h1, x2r, y2r, w2, h2;
                {
                    float s = 8.f; int n = 80;
                    x0 = (int)floorf((g.x + EPS) / s - 0.5f); if (x0 < 0) x0 = 0;
                    int xh = (int)ceilf((g.z - EPS) / s - 0.5f); if (xh > n - 1) xh = n - 1;
                    y0 = (int)floorf((g.y + EPS) / s - 0.5f); if (y0 < 0) y0 = 0;
                    int yh = (int)ceilf((g.w - EPS) / s - 0.5f); if (yh > n - 1) yh = n - 1;
                    w0 = xh - x0 + 1; if (w0 < 0) w0 = 0;
                    h0 = yh - y0 + 1; if (h0 < 0) h0 = 0;
                }
                {
                    float s = 16.f; int n = 40;
                    x1r = (int)floorf((g.x + EPS) / s - 0.5f); if (x1r < 0) x1r = 0;
                    int xh = (int)ceilf((g.z - EPS) / s - 0.5f); if (xh > n - 1) xh = n - 1;
                    y1r = (int)floorf((g.y + EPS) / s - 0.5f); if (y1r < 0) y1r = 0;
                    int yh = (int)ceilf((g.w - EPS) / s - 0.5f); if (yh > n - 1) yh = n - 1;
                    w1 = xh - x1r + 1; if (w1 < 0) w1 = 0;
                    h1 = yh - y1r + 1; if (h1 < 0) h1 = 0;
                }
                {
                    float s = 32.f; int n = 20;
                    x2r = (int)floorf((g.x + EPS) / s - 0.5f); if (x2r < 0) x2r = 0;
                    int xh = (int)ceilf((g.z - EPS) / s - 0.5f); if (xh > n - 1) xh = n - 1;
                    y2r = (int)floorf((g.y + EPS) / s - 0.5f); if (y2r < 0) y2r = 0;
                    int yh = (int)ceilf((g.w - EPS) / s - 0.5f); if (yh > n - 1) yh = n - 1;
                    w2 = xh - x2r + 1; if (w2 < 0) w2 = 0;
                    h2 = yh - y2r + 1; if (h2 < 0) h2 = 0;
                }
                int n0 = w0 * h0, n01 = n0 + w1 * h1, n012 = n01 + w2 * h2;
                int N = n012 + TOPK;               // <= ~583 + 13 <= 640
                float rw0 = __builtin_amdgcn_rcpf((float)w0);
                float rw1 = __builtin_amdgcn_rcpf((float)w1);
                float rw2 = __builtin_amdgcn_rcpf((float)w2);

                // pass A: addresses only (branchy, no loads)
                int aarr[10]; float axv[10], ayv[10];
                unsigned validm = 0;
                #pragma unroll
                for (int j = 0; j < 10; ++j) {
                    aarr[j] = 0; axv[j] = 0.f; ayv[j] = 0.f;
                    int c = lane + j * 64;
                    if (c < N) {
                        int a; float ax, ay; bool dup = false;
                        if (c < n0) {
                            int iy, ix; fdivmod(c, w0, rw0, iy, ix);
                            iy += y0; ix += x0;
                            a = iy * 80 + ix; ax = (ix + 0.5f) * 8.f; ay = (iy + 0.5f) * 8.f;
                        } else if (c < n01) {
                            int iy, ix; fdivmod(c - n0, w1, rw1, iy, ix);
                            iy += y1r; ix += x1r;
                            a = 6400 + iy * 40 + ix; ax = (ix + 0.5f) * 16.f; ay = (iy + 0.5f) * 16.f;
                        } else if (c < n012) {
                            int iy, ix; fdivmod(c - n01, w2, rw2, iy, ix);
                            iy += y2r; ix += x2r;
                            a = 8000 + iy * 20 + ix; ax = (ix + 0.5f) * 32.f; ay = (iy + 0.5f) * 32.f;
                        } else {
                            a = c - n012;          // supplement: L0 row 0, ix=a
                            ax = (a + 0.5f) * 8.f; ay = 4.0f;
                            dup = (h0 > 0) && (y0 == 0) && (w0 > 0) &&
                                  (x0 <= a) && (a <= x0 + w0 - 1);
                        }
                        if (!dup) { aarr[j] = a; axv[j] = ax; ayv[j] = ay; validm |= 1u << j; }
                    }
                }
                // pass B: all 20 gathers issued back-to-back (a=0 for invalid)
                float4 pv[10]; float sv[10];
                #pragma unroll
                for (int j = 0; j < 10; ++j) {
                    pv[j] = pb[aarr[j]];
                    sv[j] = srow[(size_t)aarr[j] * NC];
                }
                // pass C: values + packed keys
                unsigned long long key[10];
                unsigned insmask = 0;
                #pragma unroll
                for (int j = 0; j < 10; ++j) {
                    key[j] = 0ull;
                    if (validm & (1u << j)) {
                        float ov = iou_xyxy(g, pv[j]);
                        bool ins = fminf(fminf(axv[j] - g.x, ayv[j] - g.y),
                                         fminf(g.z - axv[j], g.w - ayv[j])) > EPS;
                        float o2 = ov * ov;
                        float val = ins ? sv[j] * o2 * o2 * o2 : 0.f;
                        key[j] = ((unsigned long long)__float_as_uint(val) << 32)
                               | (unsigned)(0xFFFFFFFFu - (unsigned)aarr[j]);
                        if (ins) insmask |= (1u << j);
                    }
                }
                // 13 rounds of wave argmax (exact top_k order: value desc, idx asc)
                for (int r = 0; r < TOPK; ++r) {
                    unsigned long long best = 0ull;
                    #pragma unroll
                    for (int j = 0; j < 10; ++j) if (key[j] > best) best = key[j];
                    #pragma unroll
                    for (int off = 32; off >= 1; off >>= 1) {
                        unsigned long long o = __shfl_xor(best, off, 64);
                        if (o > best) best = o;
                    }
                    #pragma unroll
                    for (int j = 0; j < 10; ++j) {
                        if (key[j] == best) {      // unique owner
                            key[j] = 0ull;
                            if ((insmask >> j) & 1u) {
                                int a = (int)(0xFFFFFFFFu - (unsigned)best);
                                atomicAdd(&cm[b * NA + a], (1u << 20) | (unsigned)mm);
                            }
                        }
                    }
                }
            }
        }
    }
    gbar(ws, 0);

    // ------------- phase 2: resolution (1 anchor per thread, exact) ----------
    int t = blockIdx.x * 256 + threadIdx.x;    // < BS*NA always (525*256 exact)
    int b = t / NA;
    int idx = 0, fg = 0, lbl;
    float al = 0.f;
    {
        unsigned c = cm[t];                    // plain load (safe post-barrier)
        int cnt = (int)(c >> 20);
        float4 p = ((const float4*)pboxes)[t];
        if (cnt == 1) { idx = (int)(c & 0xFFFFFu); fg = 1; }
        else if (cnt > 1) {
            float best = -1.f; int bmx = 0;
            for (int m = 0; m < NMB; ++m) {
                float ov = iou_xyxy(gb4[b * NMB + m], p);   // L2-resident
                if (ov > best) { best = ov; bmx = m; }
            }
            idx = bmx; fg = 1;
        }
        lbl = glabels[b * NMB + idx];
        if (lbl < 0) lbl = 0;
        float4 gbx = gb4[b * NMB + idx];
        if (fg) {
            float ov = iou_xyxy(gbx, p);
            float sc = scores[(size_t)t * NC + lbl];
            float o2 = ov * ov;
            al = sc * o2 * o2 * o2;            // UNMASKED align (matches ref)
            atomicMax(&posalign[b * NMB + idx], __float_as_uint(al));
            atomicMax(&posover[b * NMB + idx], __float_as_uint(ov));
        }
        out[OUT_LABELS + t] = (float)lbl;      // gather NOT masked by fg (ref)
        ((float4*)(out + OUT_BBOX))[t] = gbx;
        out[OUT_FG + t] = fg ? 1.f : 0.f;
    }
    gbar(ws, 1);

    // ------------- phase 3: score rows, block-cooperative coalesced ----------
    __shared__ float s_norm[256];
    __shared__ int   s_lbl[256];
    {
        float norm = 0.f; int plbl = -1;
        if (fg) {
            float pa = __uint_as_float(posalign[b * NMB + idx]);  // plain loads
            float po = __uint_as_float(posover[b * NMB + idx]);
            norm = al * po / (pa + EPS);
            plbl = lbl;
        }
        s_norm[threadIdx.x] = norm;
        s_lbl[threadIdx.x] = plbl;
        __syncthreads();
        int base = blockIdx.x * (256 * (NC / 4));
        #pragma unroll
        for (int k = 0; k < NC / 4; ++k) {
            int cidx = threadIdx.x + k * 256;
            int r = cidx / (NC / 4), q = cidx - r * (NC / 4);
            float nv = s_norm[r]; int lv = s_lbl[r];
            int c0 = q * 4;
            f32x4 w;
            w.x = (c0     == lv) ? nv : 0.f;
            w.y = (c0 + 1 == lv) ? nv : 0.f;
            w.z = (c0 + 2 == lv) ? nv : 0.f;
            w.w = (c0 + 3 == lv) ? nv : 0.f;
            ((f32x4*)(out + OUT_SCORES))[base + cidx] = w;
        }
    }
}

extern "C" void kernel_launch(void* const* d_in, const int* in_sizes, int n_in,
                              void* d_out, int out_size, void* d_ws, size_t ws_size,
                              hipStream_t stream) {
    const float* scores  = (const float*)d_in[0];   // [BS,NA,NC]
    const float* pboxes  = (const float*)d_in[1];   // [BS,NA,4]
    const float* gboxes  = (const float*)d_in[3];   // [BS,NMB,4]
    const float* maskgt  = (const float*)d_in[4];   // [BS,NMB,1]
    const int*   glabels = (const int*)d_in[5];     // [BS,NMB,1]
    float* out = (float*)d_out;

    k_init<<<(INIT_VEC + 255) / 256, 256, 0, stream>>>((uint4*)d_ws);
    k_fused<<<NBLK, 256, 0, stream>>>(scores, pboxes, gboxes, maskgt, glabels,
                                      (unsigned int*)d_ws, out);
}

// Round 15
// 69.506 us; speedup vs baseline: 4.6372x; 1.0636x over previous
//
#include <hip/hip_runtime.h>
#include <hip/hip_bf16.h>

#define BS   16
#define NA   8400
#define NMB  100
#define NC   80
#define TOPK 13
#define EPS  1e-9f
#define NBLK 512                              // deadlock-safe at worst-case 256 VGPR

typedef float f32x4 __attribute__((ext_vector_type(4)));

// output layout (floats): labels [BS,NA] | bboxes [BS,NA,4] | scores [BS,NA,NC] | fg [BS,NA]
#define OUT_LABELS 0
#define OUT_BBOX   (BS * NA)
#define OUT_SCORES (BS * NA * 5)
#define OUT_FG     (BS * NA * 5 + BS * NA * NC)

// ws (u32 units): cm[BS*NA] | posalign[1600] | posover[1600] |
//   arrive[NBLK] x 16 u32 (64B-spaced) | go[NBLK] x 16 u32
#define CM_OFF   0
#define PA_OFF   (BS * NA)                    // 134400
#define PO_OFF   (BS * NA + BS * NMB)         // 136000
#define ARR_OFF  (BS * NA + 2 * BS * NMB)     // 137600
#define GO_OFF   (ARR_OFF + NBLK * 16)        // 145792
#define INIT_U32 (GO_OFF + NBLK * 16)         // 153984
#define INIT_VEC (INIT_U32 / 4)               // 38496

__device__ __forceinline__ float iou_xyxy(float4 g, float4 p) {
    float lx = fmaxf(g.x, p.x), ly = fmaxf(g.y, p.y);
    float rx = fminf(g.z, p.z), ry = fminf(g.w, p.w);
    float w = fmaxf(rx - lx, 0.f), h = fmaxf(ry - ly, 0.f);
    float inter = w * h;
    float ag = (g.z - g.x) * (g.w - g.y);
    float ap = (p.z - p.x) * (p.w - p.y);
    return inter / (ag + ap - inter + EPS);
}

// fast unsigned divide for small c (<4096), w (<128): rcp + correction
__device__ __forceinline__ void fdivmod(int c, int w, float rw, int& q, int& r) {
    q = (int)((float)c * rw);
    r = c - q * w;
    if (r < 0) { q--; r += w; }
    else if (r >= w) { q++; r -= w; }
}

// Store-arrival grid barrier (zero atomic RMWs):
//  - arrival: each block STORES epoch to its own 64B arrive line
//  - block 0's 256 threads sweep the 512 lines in parallel (2 each)
//  - release: per-block 64B go lines, 1 poller per line
__device__ __forceinline__ void gbar(unsigned* ws, int which) {
    unsigned* arrive = ws + ARR_OFF;
    unsigned* go     = ws + GO_OFF;
    unsigned epoch = (unsigned)(which + 1);
    __syncthreads();
    if (blockIdx.x == 0) {
        if (threadIdx.x == 0)
            __hip_atomic_store(&arrive[0], epoch, __ATOMIC_RELAXED,
                               __HIP_MEMORY_SCOPE_AGENT);
        for (int i = threadIdx.x; i < NBLK; i += 256) {
            while (__hip_atomic_load(&arrive[i * 16], __ATOMIC_RELAXED,
                                     __HIP_MEMORY_SCOPE_AGENT) < epoch)
                __builtin_amdgcn_s_sleep(8);
        }
        __syncthreads();                       // all 512 arrived
        for (int i = threadIdx.x; i < NBLK; i += 256)
            __hip_atomic_store(&go[i * 16], epoch, __ATOMIC_RELAXED,
                               __HIP_MEMORY_SCOPE_AGENT);
    } else {
        if (threadIdx.x == 0) {
            __hip_atomic_store(&arrive[blockIdx.x * 16], epoch,
                               __ATOMIC_RELAXED, __HIP_MEMORY_SCOPE_AGENT);
            while (__hip_atomic_load(&go[blockIdx.x * 16], __ATOMIC_RELAXED,
                                     __HIP_MEMORY_SCOPE_AGENT) < epoch)
                __builtin_amdgcn_s_sleep(8);
        }
        __syncthreads();
    }
    asm volatile("" ::: "memory");             // compiler fence only
}

// Zero cm + posalign + posover + arrive + go lines (616 KB).
__global__ __launch_bounds__(256) void k_init(uint4* __restrict__ ws) {
    int t = blockIdx.x * 256 + threadIdx.x;
    if (t < INIT_VEC) ws[t] = make_uint4(0u, 0u, 0u, 0u);
}

// Phase-2 worker: resolution for one anchor, per-GT maxima atomics, direct
// outputs; returns (idx, fg, al, lbl) in registers for phase 3.
__device__ __forceinline__ void resolve_one(
        int t, const float* __restrict__ scores, const float4* __restrict__ pb4,
        const float4* __restrict__ gb4, const int* __restrict__ glabels,
        const unsigned* __restrict__ cm,
        unsigned* __restrict__ posalign, unsigned* __restrict__ posover,
        float* __restrict__ out, int& idx, int& fg, float& al, int& lbl) {
    int b = t / NA;
    unsigned c = cm[t];                        // plain load (safe post-barrier)
    int cnt = (int)(c >> 20);
    float4 p = pb4[t];
    idx = 0; fg = 0; al = 0.f;
    if (cnt == 1) { idx = (int)(c & 0xFFFFFu); fg = 1; }
    else if (cnt > 1) {
        // multi-GT anchor -> argmax_m IoU over ALL m (first occurrence on ties)
        float best = -1.f; int bmx = 0;
        for (int m = 0; m < NMB; ++m) {
            float ov = iou_xyxy(gb4[b * NMB + m], p);       // L2-resident
            if (ov > best) { best = ov; bmx = m; }
        }
        idx = bmx; fg = 1;
    }
    lbl = glabels[b * NMB + idx];
    if (lbl < 0) lbl = 0;
    float4 gbx = gb4[b * NMB + idx];
    if (fg) {
        float ov = iou_xyxy(gbx, p);
        float sc = scores[(size_t)t * NC + lbl];
        float o2 = ov * ov;
        al = sc * o2 * o2 * o2;                // UNMASKED align (matches ref)
        atomicMax(&posalign[b * NMB + idx], __float_as_uint(al));
        atomicMax(&posover[b * NMB + idx], __float_as_uint(ov));
    }
    out[OUT_LABELS + t] = (float)lbl;          // gather NOT masked by fg (ref)
    ((float4*)(out + OUT_BBOX))[t] = gbx;
    out[OUT_FG + t] = fg ? 1.f : 0.f;
}

// Phase-3 worker: block-cooperative coalesced score rows for one 256-anchor
// chunk (LDS redistribution; includes trailing sync for LDS reuse).
__device__ __forceinline__ void score_chunk(
        int t, int fg, int idx, float al, int lbl, int chunk,
        const unsigned* __restrict__ posalign,
        const unsigned* __restrict__ posover, float* __restrict__ out,
        float* s_norm, int* s_lbl) {
    int b = t / NA;
    float norm = 0.f; int plbl = -1;
    if (fg) {
        float pa = __uint_as_float(posalign[b * NMB + idx]);   // plain loads
        float po = __uint_as_float(posover[b * NMB + idx]);
        norm = al * po / (pa + EPS);
        plbl = lbl;
    }
    s_norm[threadIdx.x] = norm;
    s_lbl[threadIdx.x] = plbl;
    __syncthreads();
    int base = chunk * (256 * (NC / 4));
    #pragma unroll
    for (int k = 0; k < NC / 4; ++k) {
        int cidx = threadIdx.x + k * 256;
        int r = cidx / (NC / 4), q = cidx - r * (NC / 4);
        float nv = s_norm[r]; int lv = s_lbl[r];
        int c0 = q * 4;
        f32x4 w;
        w.x = (c0     == lv) ? nv : 0.f;
        w.y = (c0 + 1 == lv) ? nv : 0.f;
        w.z = (c0 + 2 == lv) ? nv : 0.f;
        w.w = (c0 + 3 == lv) ? nv : 0.f;
        ((f32x4*)(out + OUT_SCORES))[base + cidx] = w;
    }
    __syncthreads();                           // LDS safe for next chunk
}

// Persistent fused kernel: phase1 topk | bar | phase2 resolve | bar | phase3
// score. 512 blocks x 256 threads; launch_bounds(256,2) -> VGPR budget 256,
// compiler lands ~128 with NO spill of phase-1's live set (R10 evidence;
// (256,3)'s 84-VGPR squeeze left 22MB of scratch writeback in R13/R14).
// Worst-case 256 VGPR -> 2 blocks/CU -> 512 slots = NBLK -> co-resident.
// Blocks 0..12 handle a second anchor (13*256 = 134400-131072 exactly).
__global__ __launch_bounds__(256, 2) void k_fused(
        const float* __restrict__ scores, const float* __restrict__ pboxes,
        const float* __restrict__ gboxes, const float* __restrict__ maskgt,
        const int* __restrict__ glabels,
        unsigned int* __restrict__ ws, float* __restrict__ out) {
    unsigned int* cm       = ws + CM_OFF;
    unsigned int* posalign = ws + PA_OFF;
    unsigned int* posover  = ws + PO_OFF;
    const float4* gb4 = (const float4*)gboxes;
    const float4* pb4 = (const float4*)pboxes;

    // ---------------- phase 1: top-k per GT (one wave per GT) ----------------
    {
        int w = blockIdx.x * 4 + (threadIdx.x >> 6);   // 2048 waves >= 1600
        if (w < BS * NMB) {
            int bm = (w & 7) * 200 + (w >> 3);         // XCD spread
            float mg = maskgt[bm];
            float4 g = gb4[bm];
            int lbl = glabels[bm];
            if (mg > 0.f) {
                int b = bm / NMB, mm = bm - b * NMB;
                int lane = threadIdx.x & 63;
                const float* srow = scores + (size_t)b * NA * NC + lbl;
                const float4* pb = pb4 + (size_t)b * NA;

                // padded per-level index ranges; ins test is the exact filter
                int x0, y0, w0, h0, x1r, y1r, w1, h1, x2r, y2r, w2, h2;
                {
                    float s = 8.f; int n = 80;
                    x0 = (int)floorf((g.x + EPS) / s - 0.5f); if (x0 < 0) x0 = 0;
                    int xh = (int)ceilf((g.z - EPS) / s - 0.5f); if (xh > n - 1) xh = n - 1;
                    y0 = (int)floorf((g.y + EPS) / s - 0.5f); if (y0 < 0) y0 = 0;
                    int yh = (int)ceilf((g.w - EPS) / s - 0.5f); if (yh > n - 1) yh = n - 1;
                    w0 = xh - x0 + 1; if (w0 < 0) w0 = 0;
                    h0 = yh - y0 + 1; if (h0 < 0) h0 = 0;
                }
                {
                    float s = 16.f; int n = 40;
                    x1r = (int)floorf((g.x + EPS) / s - 0.5f); if (x1r < 0) x1r = 0;
                    int xh = (int)ceilf((g.z - EPS) / s - 0.5f); if (xh > n - 1) xh = n - 1;
                    y1r = (int)floorf((g.y + EPS) / s - 0.5f); if (y1r < 0) y1r = 0;
                    int yh = (int)ceilf((g.w - EPS) / s - 0.5f); if (yh > n - 1) yh = n - 1;
                    w1 = xh - x1r + 1; if (w1 < 0) w1 = 0;
                    h1 = yh - y1r + 1; if (h1 < 0) h1 = 0;
                }
                {
                    float s = 32.f; int n = 20;
                    x2r = (int)floorf((g.x + EPS) / s - 0.5f); if (x2r < 0) x2r = 0;
                    int xh = (int)ceilf((g.z - EPS) / s - 0.5f); if (xh > n - 1) xh = n - 1;
                    y2r = (int)floorf((g.y + EPS) / s - 0.5f); if (y2r < 0) y2r = 0;
                    int yh = (int)ceilf((g.w - EPS) / s - 0.5f); if (yh > n - 1) yh = n - 1;
                    w2 = xh - x2r + 1; if (w2 < 0) w2 = 0;
                    h2 = yh - y2r + 1; if (h2 < 0) h2 = 0;
                }
                int n0 = w0 * h0, n01 = n0 + w1 * h1, n012 = n01 + w2 * h2;
                int N = n012 + TOPK;               // <= ~583 + 13 <= 640
                float rw0 = __builtin_amdgcn_rcpf((float)w0);
                float rw1 = __builtin_amdgcn_rcpf((float)w1);
                float rw2 = __builtin_amdgcn_rcpf((float)w2);

                // pass A: addresses only (branchy, no loads)
                int aarr[10]; float axv[10], ayv[10];
                unsigned validm = 0;
                #pragma unroll
                for (int j = 0; j < 10; ++j) {
                    aarr[j] = 0; axv[j] = 0.f; ayv[j] = 0.f;
                    int c = lane + j * 64;
                    if (c < N) {
                        int a; float ax, ay; bool dup = false;
                        if (c < n0) {
                            int iy, ix; fdivmod(c, w0, rw0, iy, ix);
                            iy += y0; ix += x0;
                            a = iy * 80 + ix; ax = (ix + 0.5f) * 8.f; ay = (iy + 0.5f) * 8.f;
                        } else if (c < n01) {
                            int iy, ix; fdivmod(c - n0, w1, rw1, iy, ix);
                            iy += y1r; ix += x1r;
                            a = 6400 + iy * 40 + ix; ax = (ix + 0.5f) * 16.f; ay = (iy + 0.5f) * 16.f;
                        } else if (c < n012) {
                            int iy, ix; fdivmod(c - n01, w2, rw2, iy, ix);
                            iy += y2r; ix += x2r;
                            a = 8000 + iy * 20 + ix; ax = (ix + 0.5f) * 32.f; ay = (iy + 0.5f) * 32.f;
                        } else {
                            a = c - n012;          // supplement: L0 row 0, ix=a
                            ax = (a + 0.5f) * 8.f; ay = 4.0f;
                            dup = (h0 > 0) && (y0 == 0) && (w0 > 0) &&
                                  (x0 <= a) && (a <= x0 + w0 - 1);
                        }
                        if (!dup) { aarr[j] = a; axv[j] = ax; ayv[j] = ay; validm |= 1u << j; }
                    }
                }
                // pass B: all 20 gathers issued back-to-back (a=0 for invalid)
                float4 pv[10]; float sv[10];
                #pragma unroll
                for (int j = 0; j < 10; ++j) {
                    pv[j] = pb[aarr[j]];
                    sv[j] = srow[(size_t)aarr[j] * NC];
                }
                // pass C: values + packed keys
                unsigned long long key[10];
                unsigned insmask = 0;
                #pragma unroll
                for (int j = 0; j < 10; ++j) {
                    key[j] = 0ull;
                    if (validm & (1u << j)) {
                        float ov = iou_xyxy(g, pv[j]);
                        bool ins = fminf(fminf(axv[j] - g.x, ayv[j] - g.y),
                                         fminf(g.z - axv[j], g.w - ayv[j])) > EPS;
                        float o2 = ov * ov;
                        float val = ins ? sv[j] * o2 * o2 * o2 : 0.f;
                        key[j] = ((unsigned long long)__float_as_uint(val) << 32)
                               | (unsigned)(0xFFFFFFFFu - (unsigned)aarr[j]);
                        if (ins) insmask |= (1u << j);
                    }
                }
                // 13 rounds of wave argmax (exact top_k order: value desc, idx asc)
                for (int r = 0; r < TOPK; ++r) {
                    unsigned long long best = 0ull;
                    #pragma unroll
                    for (int j = 0; j < 10; ++j) if (key[j] > best) best = key[j];
                    #pragma unroll
                    for (int off = 32; off >= 1; off >>= 1) {
                        unsigned long long o = __shfl_xor(best, off, 64);
                        if (o > best) best = o;
                    }
                    #pragma unroll
                    for (int j = 0; j < 10; ++j) {
                        if (key[j] == best) {      // unique owner
                            key[j] = 0ull;
                            if ((insmask >> j) & 1u) {
                                int a = (int)(0xFFFFFFFFu - (unsigned)best);
                                atomicAdd(&cm[b * NA + a], (1u << 20) | (unsigned)mm);
                            }
                        }
                    }
                }
            }
        }
    }
    gbar(ws, 0);

    // ------------- phase 2: resolution (1-2 anchors per thread) --------------
    int t0 = blockIdx.x * 256 + threadIdx.x;
    bool second = blockIdx.x < 13;             // 13*256 covers anchors 131072..134399
    int t1 = t0 + NBLK * 256;
    int idx0, fg0, lbl0; float al0;
    resolve_one(t0, scores, pb4, gb4, glabels, cm, posalign, posover, out,
                idx0, fg0, al0, lbl0);
    int idx1 = 0, fg1 = 0, lbl1 = 0; float al1 = 0.f;
    if (second)
        resolve_one(t1, scores, pb4, gb4, glabels, cm, posalign, posover, out,
                    idx1, fg1, al1, lbl1);
    gbar(ws, 1);

    // ------------- phase 3: score rows, block-cooperative coalesced ----------
    __shared__ float s_norm[256];
    __shared__ int   s_lbl[256];
    score_chunk(t0, fg0, idx0, al0, lbl0, blockIdx.x,
                posalign, posover, out, s_norm, s_lbl);
    if (second)
        score_chunk(t1, fg1, idx1, al1, lbl1, NBLK + blockIdx.x,
                    posalign, posover, out, s_norm, s_lbl);
}

extern "C" void kernel_launch(void* const* d_in, const int* in_sizes, int n_in,
                              void* d_out, int out_size, void* d_ws, size_t ws_size,
                              hipStream_t stream) {
    const float* scores  = (const float*)d_in[0];   // [BS,NA,NC]
    const float* pboxes  = (const float*)d_in[1];   // [BS,NA,4]
    const float* gboxes  = (const float*)d_in[3];   // [BS,NMB,4]
    const float* maskgt  = (const float*)d_in[4];   // [BS,NMB,1]
    const int*   glabels = (const int*)d_in[5];     // [BS,NMB,1]
    float* out = (float*)d_out;

    k_init<<<(INIT_VEC + 255) / 256, 256, 0, stream>>>((uint4*)d_ws);
    k_fused<<<NBLK, 256, 0, stream>>>(scores, pboxes, gboxes, maskgt, glabels,
                                      (unsigned int*)d_ws, out);
}

// Round 16
// 62.302 us; speedup vs baseline: 5.1734x; 1.1156x over previous
//
#include <hip/hip_runtime.h>
#include <hip/hip_bf16.h>

#define BS   16
#define NA   8400
#define NMB  100
#define NC   80
#define TOPK 13
#define EPS  1e-9f
#define NBLK 512                              // deadlock-safe at worst-case 256 VGPR

typedef float f32x4 __attribute__((ext_vector_type(4)));

// output layout (floats): labels [BS,NA] | bboxes [BS,NA,4] | scores [BS,NA,NC] | fg [BS,NA]
#define OUT_LABELS 0
#define OUT_BBOX   (BS * NA)
#define OUT_SCORES (BS * NA * 5)
#define OUT_FG     (BS * NA * 5 + BS * NA * NC)

// ws (u32 units): cm[BS*NA] | posalign[1600] | posover[1600] |
//   arrive[NBLK] x 16 u32 (64B-spaced) | go[NBLK] x 16 u32
#define CM_OFF   0
#define PA_OFF   (BS * NA)                    // 134400
#define PO_OFF   (BS * NA + BS * NMB)         // 136000
#define ARR_OFF  (BS * NA + 2 * BS * NMB)     // 137600
#define GO_OFF   (ARR_OFF + NBLK * 16)        // 145792
#define INIT_U32 (GO_OFF + NBLK * 16)         // 153984
#define INIT_VEC (INIT_U32 / 4)               // 38496

__device__ __forceinline__ float iou_xyxy(float4 g, float4 p) {
    float lx = fmaxf(g.x, p.x), ly = fmaxf(g.y, p.y);
    float rx = fminf(g.z, p.z), ry = fminf(g.w, p.w);
    float w = fmaxf(rx - lx, 0.f), h = fmaxf(ry - ly, 0.f);
    float inter = w * h;
    float ag = (g.z - g.x) * (g.w - g.y);
    float ap = (p.z - p.x) * (p.w - p.y);
    return inter / (ag + ap - inter + EPS);
}

// fast unsigned divide for small c (<4096), w (<128): rcp + correction
__device__ __forceinline__ void fdivmod(int c, int w, float rw, int& q, int& r) {
    q = (int)((float)c * rw);
    r = c - q * w;
    if (r < 0) { q--; r += w; }
    else if (r >= w) { q++; r -= w; }
}

// Bijective chunk permutation over 525 slots (m204-style): slot s -> chunk,
// such that all chunks of XCD x (s%8==x) form a CONTIGUOUS range = the
// anchors of batches 2x,2x+1. 525 = 5*66 + 3*65.
__device__ __forceinline__ int chunk_perm(int s) {
    int x = s & 7, pos = s >> 3;
    return (x < 5 ? x * 66 : 330 + (x - 5) * 65) + pos;
}

// Store-arrival grid barrier (zero atomic RMWs):
//  - arrival: each block STORES epoch to its own 64B arrive line
//  - block 0's 256 threads sweep the 512 lines in parallel (2 each)
//  - release: per-block 64B go lines, 1 poller per line
__device__ __forceinline__ void gbar(unsigned* ws, int which) {
    unsigned* arrive = ws + ARR_OFF;
    unsigned* go     = ws + GO_OFF;
    unsigned epoch = (unsigned)(which + 1);
    __syncthreads();
    if (blockIdx.x == 0) {
        if (threadIdx.x == 0)
            __hip_atomic_store(&arrive[0], epoch, __ATOMIC_RELAXED,
                               __HIP_MEMORY_SCOPE_AGENT);
        for (int i = threadIdx.x; i < NBLK; i += 256) {
            while (__hip_atomic_load(&arrive[i * 16], __ATOMIC_RELAXED,
                                     __HIP_MEMORY_SCOPE_AGENT) < epoch)
                __builtin_amdgcn_s_sleep(8);
        }
        __syncthreads();                       // all 512 arrived
        for (int i = threadIdx.x; i < NBLK; i += 256)
            __hip_atomic_store(&go[i * 16], epoch, __ATOMIC_RELAXED,
                               __HIP_MEMORY_SCOPE_AGENT);
    } else {
        if (threadIdx.x == 0) {
            __hip_atomic_store(&arrive[blockIdx.x * 16], epoch,
                               __ATOMIC_RELAXED, __HIP_MEMORY_SCOPE_AGENT);
            while (__hip_atomic_load(&go[blockIdx.x * 16], __ATOMIC_RELAXED,
                                     __HIP_MEMORY_SCOPE_AGENT) < epoch)
                __builtin_amdgcn_s_sleep(8);
        }
        __syncthreads();
    }
    asm volatile("" ::: "memory");             // compiler fence only
}

// Zero cm + posalign + posover + arrive + go lines (616 KB).
__global__ __launch_bounds__(256) void k_init(uint4* __restrict__ ws) {
    int t = blockIdx.x * 256 + threadIdx.x;
    if (t < INIT_VEC) ws[t] = make_uint4(0u, 0u, 0u, 0u);
}

// Phase-2 worker: resolution for one anchor, per-GT maxima atomics, direct
// outputs; returns (idx, fg, al, lbl) in registers for phase 3.
__device__ __forceinline__ void resolve_one(
        int t, const float* __restrict__ scores, const float4* __restrict__ pb4,
        const float4* __restrict__ gb4, const int* __restrict__ glabels,
        const unsigned* __restrict__ cm,
        unsigned* __restrict__ posalign, unsigned* __restrict__ posover,
        float* __restrict__ out, int& idx, int& fg, float& al, int& lbl) {
    int b = t / NA;
    unsigned c = cm[t];                        // plain load (safe post-barrier)
    int cnt = (int)(c >> 20);
    float4 p = pb4[t];
    idx = 0; fg = 0; al = 0.f;
    if (cnt == 1) { idx = (int)(c & 0xFFFFFu); fg = 1; }
    else if (cnt > 1) {
        // multi-GT anchor -> argmax_m IoU over ALL m (first occurrence on ties)
        float best = -1.f; int bmx = 0;
        for (int m = 0; m < NMB; ++m) {
            float ov = iou_xyxy(gb4[b * NMB + m], p);       // L2-resident
            if (ov > best) { best = ov; bmx = m; }
        }
        idx = bmx; fg = 1;
    }
    lbl = glabels[b * NMB + idx];
    if (lbl < 0) lbl = 0;
    float4 gbx = gb4[b * NMB + idx];
    if (fg) {
        float ov = iou_xyxy(gbx, p);
        float sc = scores[(size_t)t * NC + lbl];
        float o2 = ov * ov;
        al = sc * o2 * o2 * o2;                // UNMASKED align (matches ref)
        atomicMax(&posalign[b * NMB + idx], __float_as_uint(al));
        atomicMax(&posover[b * NMB + idx], __float_as_uint(ov));
    }
    out[OUT_LABELS + t] = (float)lbl;          // gather NOT masked by fg (ref)
    ((float4*)(out + OUT_BBOX))[t] = gbx;
    out[OUT_FG + t] = fg ? 1.f : 0.f;
}

// Phase-3 worker: block-cooperative coalesced score rows for one 256-anchor
// chunk (LDS redistribution; includes trailing sync for LDS reuse).
__device__ __forceinline__ void score_chunk(
        int t, int fg, int idx, float al, int lbl, int chunk,
        const unsigned* __restrict__ posalign,
        const unsigned* __restrict__ posover, float* __restrict__ out,
        float* s_norm, int* s_lbl) {
    int b = t / NA;
    float norm = 0.f; int plbl = -1;
    if (fg) {
        float pa = __uint_as_float(posalign[b * NMB + idx]);   // plain loads
        float po = __uint_as_float(posover[b * NMB + idx]);
        norm = al * po / (pa + EPS);
        plbl = lbl;
    }
    s_norm[threadIdx.x] = norm;
    s_lbl[threadIdx.x] = plbl;
    __syncthreads();
    int base = chunk * (256 * (NC / 4));
    #pragma unroll
    for (int k = 0; k < NC / 4; ++k) {
        int cidx = threadIdx.x + k * 256;
        int r = cidx / (NC / 4), q = cidx - r * (NC / 4);
        float nv = s_norm[r]; int lv = s_lbl[r];
        int c0 = q * 4;
        f32x4 w;
        w.x = (c0     == lv) ? nv : 0.f;
        w.y = (c0 + 1 == lv) ? nv : 0.f;
        w.z = (c0 + 2 == lv) ? nv : 0.f;
        w.w = (c0 + 3 == lv) ? nv : 0.f;
        ((f32x4*)(out + OUT_SCORES))[base + cidx] = w;
    }
    __syncthreads();                           // LDS safe for next chunk
}

// Persistent fused kernel with XCD<->batch affinity: XCD x (blockIdx%8) owns
// batches 2x,2x+1 in ALL phases -> per-XCD L2 working set ~5.4MB (scores for
// 2 batches) instead of 43MB. Phase-1 score gathers (~1M 64B lines) and
// phase-2 score/label/box gathers then hit L2, not L3.
// 512 blocks x 256 threads; launch_bounds(256,2) -> ~128 VGPR, no spill
// (R15-verified: WRITE_SIZE clean 46.5MB); 2 blocks/CU -> co-resident.
__global__ __launch_bounds__(256, 2) void k_fused(
        const float* __restrict__ scores, const float* __restrict__ pboxes,
        const float* __restrict__ gboxes, const float* __restrict__ maskgt,
        const int* __restrict__ glabels,
        unsigned int* __restrict__ ws, float* __restrict__ out) {
    unsigned int* cm       = ws + CM_OFF;
    unsigned int* posalign = ws + PA_OFF;
    unsigned int* posover  = ws + PO_OFF;
    const float4* gb4 = (const float4*)gboxes;
    const float4* pb4 = (const float4*)pboxes;

    // ---------------- phase 1: top-k per GT (one wave per GT) ----------------
    {
        int local = (blockIdx.x >> 3) * 4 + (threadIdx.x >> 6);  // 0..255 per XCD
        if (local < 2 * NMB) {                 // 200 GTs per XCD (2 batches)
            int bm = (blockIdx.x & 7) * (2 * NMB) + local;
            float mg = maskgt[bm];
            float4 g = gb4[bm];
            int lbl = glabels[bm];
            if (mg > 0.f) {
                int b = bm / NMB, mm = bm - b * NMB;
                int lane = threadIdx.x & 63;
                const float* srow = scores + (size_t)b * NA * NC + lbl;
                const float4* pb = pb4 + (size_t)b * NA;

                // padded per-level index ranges; ins test is the exact filter
                int x0, y0, w0, h0, x1r, y1r, w1, h1, x2r, y2r, w2, h2;
                {
                    float s = 8.f; int n = 80;
                    x0 = (int)floorf((g.x + EPS) / s - 0.5f); if (x0 < 0) x0 = 0;
                    int xh = (int)ceilf((g.z - EPS) / s - 0.5f); if (xh > n - 1) xh = n - 1;
                    y0 = (int)floorf((g.y + EPS) / s - 0.5f); if (y0 < 0) y0 = 0;
                    int yh = (int)ceilf((g.w - EPS) / s - 0.5f); if (yh > n - 1) yh = n - 1;
                    w0 = xh - x0 + 1; if (w0 < 0) w0 = 0;
                    h0 = yh - y0 + 1; if (h0 < 0) h0 = 0;
                }
                {
                    float s = 16.f; int n = 40;
                    x1r = (int)floorf((g.x + EPS) / s - 0.5f); if (x1r < 0) x1r = 0;
                    int xh = (int)ceilf((g.z - EPS) / s - 0.5f); if (xh > n - 1) xh = n - 1;
                    y1r = (int)floorf((g.y + EPS) / s - 0.5f); if (y1r < 0) y1r = 0;
                    int yh = (int)ceilf((g.w - EPS) / s - 0.5f); if (yh > n - 1) yh = n - 1;
                    w1 = xh - x1r + 1; if (w1 < 0) w1 = 0;
                    h1 = yh - y1r + 1; if (h1 < 0) h1 = 0;
                }
                {
                    float s = 32.f; int n = 20;
                    x2r = (int)floorf((g.x + EPS) / s - 0.5f); if (x2r < 0) x2r = 0;
                    int xh = (int)ceilf((g.z - EPS) / s - 0.5f); if (xh > n - 1) xh = n - 1;
                    y2r = (int)floorf((g.y + EPS) / s - 0.5f); if (y2r < 0) y2r = 0;
                    int yh = (int)ceilf((g.w - EPS) / s - 0.5f); if (yh > n - 1) yh = n - 1;
                    w2 = xh - x2r + 1; if (w2 < 0) w2 = 0;
                    h2 = yh - y2r + 1; if (h2 < 0) h2 = 0;
                }
                int n0 = w0 * h0, n01 = n0 + w1 * h1, n012 = n01 + w2 * h2;
                int N = n012 + TOPK;               // <= ~583 + 13 <= 640
                float rw0 = __builtin_amdgcn_rcpf((float)w0);
                float rw1 = __builtin_amdgcn_rcpf((float)w1);
                float rw2 = __builtin_amdgcn_rcpf((float)w2);

                // pass A: addresses only (branchy, no loads)
                int aarr[10]; float axv[10], ayv[10];
                unsigned validm = 0;
                #pragma unroll
                for (int j = 0; j < 10; ++j) {
                    aarr[j] = 0; axv[j] = 0.f; ayv[j] = 0.f;
                    int c = lane + j * 64;
                    if (c < N) {
                        int a; float ax, ay; bool dup = false;
                        if (c < n0) {
                            int iy, ix; fdivmod(c, w0, rw0, iy, ix);
                            iy += y0; ix += x0;
                            a = iy * 80 + ix; ax = (ix + 0.5f) * 8.f; ay = (iy + 0.5f) * 8.f;
                        } else if (c < n01) {
                            int iy, ix; fdivmod(c - n0, w1, rw1, iy, ix);
                            iy += y1r; ix += x1r;
                            a = 6400 + iy * 40 + ix; ax = (ix + 0.5f) * 16.f; ay = (iy + 0.5f) * 16.f;
                        } else if (c < n012) {
                            int iy, ix; fdivmod(c - n01, w2, rw2, iy, ix);
                            iy += y2r; ix += x2r;
                            a = 8000 + iy * 20 + ix; ax = (ix + 0.5f) * 32.f; ay = (iy + 0.5f) * 32.f;
                        } else {
                            a = c - n012;          // supplement: L0 row 0, ix=a
                            ax = (a + 0.5f) * 8.f; ay = 4.0f;
                            dup = (h0 > 0) && (y0 == 0) && (w0 > 0) &&
                                  (x0 <= a) && (a <= x0 + w0 - 1);
                        }
                        if (!dup) { aarr[j] = a; axv[j] = ax; ayv[j] = ay; validm |= 1u << j; }
                    }
                }
                // pass B: all 20 gathers issued back-to-back (a=0 for invalid)
                float4 pv[10]; float sv[10];
                #pragma unroll
                for (int j = 0; j < 10; ++j) {
                    pv[j] = pb[aarr[j]];
                    sv[j] = srow[(size_t)aarr[j] * NC];
                }
                // pass C: values + packed keys
                unsigned long long key[10];
                unsigned insmask = 0;
                #pragma unroll
                for (int j = 0; j < 10; ++j) {
                    key[j] = 0ull;
                    if (validm & (1u << j)) {
                        float ov = iou_xyxy(g, pv[j]);
                        bool ins = fminf(fminf(axv[j] - g.x, ayv[j] - g.y),
                                         fminf(g.z - axv[j], g.w - ayv[j])) > EPS;
                        float o2 = ov * ov;
                        float val = ins ? sv[j] * o2 * o2 * o2 : 0.f;
                        key[j] = ((unsigned long long)__float_as_uint(val) << 32)
                               | (unsigned)(0xFFFFFFFFu - (unsigned)aarr[j]);
                        if (ins) insmask |= (1u << j);
                    }
                }
                // 13 rounds of wave argmax (exact top_k order: value desc, idx asc)
                for (int r = 0; r < TOPK; ++r) {
                    unsigned long long best = 0ull;
                    #pragma unroll
                    for (int j = 0; j < 10; ++j) if (key[j] > best) best = key[j];
                    #pragma unroll
                    for (int off = 32; off >= 1; off >>= 1) {
                        unsigned long long o = __shfl_xor(best, off, 64);
                        if (o > best) best = o;
                    }
                    #pragma unroll
                    for (int j = 0; j < 10; ++j) {
                        if (key[j] == best) {      // unique owner
                            key[j] = 0ull;
                            if ((insmask >> j) & 1u) {
                                int a = (int)(0xFFFFFFFFu - (unsigned)best);
                                atomicAdd(&cm[b * NA + a], (1u << 20) | (unsigned)mm);
                            }
                        }
                    }
                }
            }
        }
    }
    gbar(ws, 0);

    // ------------- phase 2: resolution (1-2 anchors per thread) --------------
    // chunk_perm keeps each XCD on the anchors of ITS batch pair (L2 reuse
    // of the scores/pboxes lines pulled in phase 1).
    int chunk0 = chunk_perm(blockIdx.x);
    bool second = blockIdx.x < 13;             // slots 512..524 -> 13 extra chunks
    int chunk1 = second ? chunk_perm(NBLK + blockIdx.x) : 0;
    int t0 = chunk0 * 256 + threadIdx.x;
    int t1 = chunk1 * 256 + threadIdx.x;
    int idx0, fg0, lbl0; float al0;
    resolve_one(t0, scores, pb4, gb4, glabels, cm, posalign, posover, out,
                idx0, fg0, al0, lbl0);
    int idx1 = 0, fg1 = 0, lbl1 = 0; float al1 = 0.f;
    if (second)
        resolve_one(t1, scores, pb4, gb4, glabels, cm, posalign, posover, out,
                    idx1, fg1, al1, lbl1);
    gbar(ws, 1);

    // ------------- phase 3: score rows, block-cooperative coalesced ----------
    __shared__ float s_norm[256];
    __shared__ int   s_lbl[256];
    score_chunk(t0, fg0, idx0, al0, lbl0, chunk0,
                posalign, posover, out, s_norm, s_lbl);
    if (second)
        score_chunk(t1, fg1, idx1, al1, lbl1, chunk1,
                    posalign, posover, out, s_norm, s_lbl);
}

extern "C" void kernel_launch(void* const* d_in, const int* in_sizes, int n_in,
                              void* d_out, int out_size, void* d_ws, size_t ws_size,
                              hipStream_t stream) {
    const float* scores  = (const float*)d_in[0];   // [BS,NA,NC]
    const float* pboxes  = (const float*)d_in[1];   // [BS,NA,4]
    const float* gboxes  = (const float*)d_in[3];   // [BS,NMB,4]
    const float* maskgt  = (const float*)d_in[4];   // [BS,NMB,1]
    const int*   glabels = (const int*)d_in[5];     // [BS,NMB,1]
    float* out = (float*)d_out;

    k_init<<<(INIT_VEC + 255) / 256, 256, 0, stream>>>((uint4*)d_ws);
    k_fused<<<NBLK, 256, 0, stream>>>(scores, pboxes, gboxes, maskgt, glabels,
                                      (unsigned int*)d_ws, out);
}